// Round 6
// baseline (286.649 us; speedup 1.0000x reference)
//
#include <hip/hip_runtime.h>

// B=2, S=2048, D=1024, H=16, DK=64
// out = attn_mean @ vs @ Wo  (Wv shared across heads => mean_h(attn_h @ vs) = attn_mean @ vs)
// attn_mean[b,s,t] = (1/H) sum_h exp(score)/denom  -- no max-subtraction (scores bounded ~|2.5|)
// qs/ks layout: [b*S+s][h*64+dk]  (concatenated-head GEMM output)
// k_denom/k_attn: mfma_f32_32x32x16_bf16 (halved LDS-read bytes/output vs 16x16, r5) with
// SPLIT-K independent chains (r6): dA over k4={0,1}, dB over k4={2,3}, exp2(dA+dB).
// r5's 4-deep dependent chain collapsed ILP (2 chains/wave, dep-latency exposed at
// 4 waves/SIMD) -> 25us of stall. Split-K restores r0's 2-deep chain depth.
// 32x32 frag layouts (HW-verified m74/m101):
//   A/B lane l: row/col = l&31, k = (l>>5)*8 + j   (within each K=16 step)
//   C/D: col = lane&31, row = (reg&3) + 8*(reg>>2) + 4*(lane>>5)
// K-tile LDS layout 32-FRAG-MAJOR: unit u = frag*64 + khalf*32 + t31, frag = t5*4 + k4
//   (t = t5*32 + t31, dk = k4*16 + khalf*8) -> reader addr = frag*1KB + lane*16B,
//   contiguous per frag, conflict-free ds_read_b128.
#define B_ 2
#define S_ 2048
#define D_ 1024
#define H_ 16
#define DK_ 64

typedef __bf16 bf8 __attribute__((ext_vector_type(8)));
typedef float f4 __attribute__((ext_vector_type(4)));
typedef float f16f __attribute__((ext_vector_type(16)));
typedef unsigned short u16x8 __attribute__((ext_vector_type(8)));

__device__ __forceinline__ unsigned short f2bf_bits(float f) {
  unsigned int u = __float_as_uint(f);
  return (unsigned short)((u + 0x7fffu + ((u >> 16) & 1u)) >> 16);
}

__device__ __forceinline__ bf8 pack_bf8(f4 lo, f4 hi) {
  u16x8 u;
  u[0] = f2bf_bits(lo[0]); u[1] = f2bf_bits(lo[1]);
  u[2] = f2bf_bits(lo[2]); u[3] = f2bf_bits(lo[3]);
  u[4] = f2bf_bits(hi[0]); u[5] = f2bf_bits(hi[1]);
  u[6] = f2bf_bits(hi[2]); u[7] = f2bf_bits(hi[3]);
  union { u16x8 u; bf8 b; } x; x.u = u; return x.b;
}

__device__ __forceinline__ bf8 ldb(const unsigned short* p) {
  return *reinterpret_cast<const bf8*>(p);
}

__device__ __forceinline__ void stage16(const void* g, void* l) {
  __builtin_amdgcn_global_load_lds(
      (const __attribute__((address_space(1))) void*)g,
      (__attribute__((address_space(3))) void*)l, 16, 0, 0);
}

#define MFMA(a, b, c) __builtin_amdgcn_mfma_f32_16x16x32_bf16((a), (b), (c), 0, 0, 0)
#define MFMA32(a, b, c) __builtin_amdgcn_mfma_f32_32x32x16_bf16((a), (b), (c), 0, 0, 0)

// ---- merged prep: cast q,k -> bf16 rows; LDS-tiled transpose-cast weights ----
// blocks 0..4095: cast q/k | 4096..4351: wq/wk 64x64 tiles | 4352..4367: wv | 4368..4383: wo
__global__ void k_prep(const float* __restrict__ q, const float* __restrict__ k,
                       const float* __restrict__ wq, const float* __restrict__ wk,
                       const float* __restrict__ wv, const float* __restrict__ wo,
                       unsigned short* __restrict__ qb, unsigned short* __restrict__ kb,
                       unsigned short* __restrict__ wqt, unsigned short* __restrict__ wkt,
                       unsigned short* __restrict__ wvt, unsigned short* __restrict__ wot) {
  __shared__ float tl[64 * 65];
  int bid = blockIdx.x, tid = threadIdx.x;
  const int rr = tid >> 6, cc = tid & 63;
  if (bid < 4096) {
    int which = bid >> 11;
    long i = ((long)(bid & 2047) * 256 + tid) * 8;
    const float* src = which ? k : q;
    unsigned short* dst = which ? kb : qb;
    f4 lo = *reinterpret_cast<const f4*>(src + i);
    f4 hi = *reinterpret_cast<const f4*>(src + i + 4);
    *reinterpret_cast<bf8*>(dst + i) = pack_bf8(lo, hi);
  } else if (bid < 4352) {
    // Wq/Wk [h][d][n=dk] -> [h][n][d], 64x64 f32 tile via LDS (coalesced both ways)
    int blk = bid - 4096;
    int h = blk >> 4, d0 = (blk & 15) * 64;
    for (int m = 0; m < 2; ++m) {
      const float* src = m ? wk : wq;
      unsigned short* dst = m ? wkt : wqt;
      if (m) __syncthreads();
#pragma unroll
      for (int it = 0; it < 16; ++it) {
        int d = it * 4 + rr;
        tl[cc * 65 + d] = src[(long)h * 65536 + (d0 + d) * 64 + cc];
      }
      __syncthreads();
#pragma unroll
      for (int it = 0; it < 16; ++it) {
        int n = it * 4 + rr;
        dst[(long)h * 65536 + n * 1024 + d0 + cc] = f2bf_bits(tl[n * 65 + cc]);
      }
    }
  } else if (bid < 4368) {
    // Wv [d][n=dk] -> [n][d]
    int d0 = (bid - 4352) * 64;
#pragma unroll
    for (int it = 0; it < 16; ++it) {
      int d = it * 4 + rr;
      tl[cc * 65 + d] = wv[(long)(d0 + d) * 64 + cc];
    }
    __syncthreads();
#pragma unroll
    for (int it = 0; it < 16; ++it) {
      int n = it * 4 + rr;
      wvt[(long)n * 1024 + d0 + cc] = f2bf_bits(tl[n * 65 + cc]);
    }
  } else {
    // Wo [kk][dd] -> [dd][kk]
    int d0 = (bid - 4368) * 64;
#pragma unroll
    for (int it = 0; it < 16; ++it) {
      int kk = it * 4 + rr;
      tl[cc * 65 + kk] = wo[(long)kk * 1024 + d0 + cc];   // tl[ddl][kk]
    }
    __syncthreads();
#pragma unroll
    for (int it = 0; it < 16; ++it) {
      int ddl = it * 4 + rr;
      wot[(long)(d0 + ddl) * 64 + cc] = f2bf_bits(tl[ddl * 65 + cc]);
    }
  }
}

// ---- GEMM: C[4096][1024] = X @ W^T, 128x128 tile, BK=32, fragment-major LDS (m97 geometry) ----
// grid (32 m-tiles, 8 n-tiles, which), block 256 (4 waves 2x2; wave = 64m x 64n, 4x4 MFMA)
__global__ __launch_bounds__(256) void k_gemm_qk(
    const unsigned short* __restrict__ qb, const unsigned short* __restrict__ kb,
    const unsigned short* __restrict__ wqt, const unsigned short* __restrict__ wkt,
    unsigned short* __restrict__ qsb, unsigned short* __restrict__ ksb) {
  __shared__ unsigned short lds[8192];          // A 8 tiles @0 (tile*512), B 8 tiles @4096
  const int tid = threadIdx.x, wave = tid >> 6, lane = tid & 63;
  const int l15 = lane & 15, quad = lane >> 4;
  const int m0 = blockIdx.x * 128, n0 = blockIdx.y * 128;
  const int which = blockIdx.z;
  const unsigned short* A = which ? kb : qb;
  const unsigned short* W = which ? wkt : wqt;
  unsigned short* C = which ? ksb : qsb;
  const float scale = which ? 1.0f : 0.18033688011112042f;  // log2(e)/8 folded into qs
  const int wr = wave >> 1, wc = wave & 1;

  f4 acc[4][4];
#pragma unroll
  for (int i = 0; i < 4; ++i)
#pragma unroll
    for (int j = 0; j < 4; ++j) acc[i][j] = f4{0.f, 0.f, 0.f, 0.f};

  // staging decode: u = i*256+tid; tile=u>>6 (st + i*4), quad=(u>>4)&3, l15=u&15
  const int sl15 = tid & 15, squad = (tid >> 4) & 3, st = tid >> 6;
  const unsigned short* gA = A + (long)(m0 + st * 16 + sl15) * D_ + squad * 8;
  const unsigned short* gB = W + (long)(n0 + st * 16 + sl15) * D_ + squad * 8;

  for (int k0 = 0; k0 < D_; k0 += 32) {
    stage16(gA + k0, lds + tid * 8);                       // A tiles 0..3
    stage16(gA + 64 * D_ + k0, lds + 2048 + tid * 8);      // A tiles 4..7
    stage16(gB + k0, lds + 4096 + tid * 8);                // B tiles 0..3
    stage16(gB + 64 * D_ + k0, lds + 6144 + tid * 8);      // B tiles 4..7
    __syncthreads();
    bf8 aF[4], bF[4];
#pragma unroll
    for (int mi = 0; mi < 4; ++mi)
      aF[mi] = ldb(lds + (wr * 4 + mi) * 512 + lane * 8);
#pragma unroll
    for (int ni = 0; ni < 4; ++ni)
      bF[ni] = ldb(lds + 4096 + (wc * 4 + ni) * 512 + lane * 8);
#pragma unroll
    for (int mi = 0; mi < 4; ++mi)
#pragma unroll
      for (int ni = 0; ni < 4; ++ni)
        acc[mi][ni] = MFMA(aF[mi], bF[ni], acc[mi][ni]);
    __syncthreads();
  }
#pragma unroll
  for (int mi = 0; mi < 4; ++mi)
#pragma unroll
    for (int r = 0; r < 4; ++r) {
      long row = m0 + wr * 64 + mi * 16 + quad * 4 + r;
#pragma unroll
      for (int ni = 0; ni < 4; ++ni)
        C[row * D_ + n0 + wc * 64 + ni * 16 + l15] = f2bf_bits(acc[mi][ni][r] * scale);
    }
}

// ---- V projection split-K: partial[kc][row][64] f32, kc chunk = 256 ----
// grid (64 rowgroups of 64, 4 kc), block 256
__global__ __launch_bounds__(256) void k_pv(
    const float* __restrict__ v, const unsigned short* __restrict__ wvt,
    float* __restrict__ pv) {
  const int tid = threadIdx.x, wave = tid >> 6, lane = tid & 63;
  const int l15 = lane & 15, quad = lane >> 4;
  const int rg = blockIdx.x, kc = blockIdx.y;
  const int row0 = rg * 64 + wave * 16;
  const float* arow = v + (long)(row0 + l15) * D_ + kc * 256 + quad * 8;
  const unsigned short* wbase = wvt + kc * 256 + quad * 8;
  f4 acc[4];
  for (int i = 0; i < 4; ++i) acc[i] = f4{0.f, 0.f, 0.f, 0.f};
  for (int k0 = 0; k0 < 256; k0 += 32) {
    f4 alo = *reinterpret_cast<const f4*>(arow + k0);
    f4 ahi = *reinterpret_cast<const f4*>(arow + k0 + 4);
    bf8 a = pack_bf8(alo, ahi);
#pragma unroll
    for (int i = 0; i < 4; ++i) {
      bf8 bf = ldb(wbase + (long)(i * 16 + l15) * D_ + k0);
      acc[i] = MFMA(a, bf, acc[i]);
    }
  }
#pragma unroll
  for (int i = 0; i < 4; ++i)
#pragma unroll
    for (int r = 0; r < 4; ++r)
      pv[((long)kc * 4096 + row0 + quad * 4 + r) * 64 + i * 16 + l15] = acc[i][r];
}

// reduce 4 k-partials -> vst[b][dk][t] bf16 (writes coalesced over t)
__global__ void k_vred(const float* __restrict__ pv, unsigned short* __restrict__ vst) {
  int e = blockIdx.x * 256 + threadIdx.x;      // e = (b*64+dk)*2048 + t
  int t = e & 2047, dk = (e >> 11) & 63, b = e >> 17;
  long row = (long)b * S_ + t;
  float s = pv[row * 64 + dk] + pv[(4096 + row) * 64 + dk] +
            pv[(8192 + row) * 64 + dk] + pv[(12288 + row) * 64 + dk];
  vst[e] = f2bf_bits(s);
}

// ---- pass 1: recip[b,h,s] = 1/(H * sum_t exp2(qs.ks)) ----
// grid (16 s-tiles of 128, H, B) = 512 blocks, block 512 = 8 waves split 4s x 2t.
// 32x32x16 MFMA, split-K chains (dA: k4=0,1 | dB: k4=2,3), 2-phase dbuf staging.
__global__ __launch_bounds__(512) void k_denom(
    const unsigned short* __restrict__ qsb, const unsigned short* __restrict__ ksb,
    float* __restrict__ recip) {
  __shared__ unsigned short lds[16384];         // 2 x 16KB (128t x 64dk, 32-frag-major)
  __shared__ float red[2][4][32];               // [wt][ws][row]
  const int tid = threadIdx.x, wave = tid >> 6, lane = tid & 63;
  const int l31 = lane & 31, lh = lane >> 5;
  const int ws = wave >> 1, wt = wave & 1;
  const int stile = blockIdx.x, h = blockIdx.y, b = blockIdx.z;
  const int s0 = stile * 128 + ws * 32;

  // A-frags: Q rows s0+l31, k = k4*16 + lh*8 (h fixed per block -> hoisted)
  const unsigned short* qrow = qsb + ((long)(b * S_) + s0 + l31) * D_ + h * 64 + lh * 8;
  bf8 aF[4];
#pragma unroll
  for (int k4 = 0; k4 < 4; ++k4) aF[k4] = ldb(qrow + k4 * 16);

  // staging decode: u = i*512+tid; t31=u&31, khalf=(u>>5)&1, frag=u>>6 (k4=frag&3, t5=frag>>2)
  const int t31s = tid & 31, khs = (tid >> 5) & 1, frs = (tid >> 6) & 7;
  const unsigned short* g0 =
      ksb + ((long)(b * S_) + (frs >> 2) * 32 + t31s) * D_ + h * 64 + (frs & 3) * 16 + khs * 8;

  // prologue: stage t-tile 0 into buf0
  stage16(g0, lds + tid * 8);
  stage16(g0 + 64 * D_, lds + 4096 + tid * 8);   // frags 8..15: t5 += 2
  asm volatile("s_waitcnt vmcnt(0)" ::: "memory");
  __builtin_amdgcn_s_barrier();
  int cur = 0;

  f16f sum;
#pragma unroll
  for (int r = 0; r < 16; ++r) sum[r] = 0.f;

  for (int it = 0; it < 16; ++it) {
    if (it + 1 < 16) {
      const unsigned short* gn = g0 + (long)(it + 1) * 128 * D_;
      unsigned short* nb = lds + (cur ^ 1) * 8192;
      stage16(gn, nb + tid * 8);
      stage16(gn + 64 * D_, nb + 4096 + tid * 8);
    }
    const unsigned short* base = lds + cur * 8192 + wt * 4096;  // wave's 8 frags (t5 = 2wt, 2wt+1)
    __builtin_amdgcn_s_setprio(1);
#pragma unroll
    for (int t5 = 0; t5 < 2; ++t5) {
      f16f dA, dB;
#pragma unroll
      for (int r = 0; r < 16; ++r) { dA[r] = 0.f; dB[r] = 0.f; }
      dA = MFMA32(aF[0], ldb(base + t5 * 2048 + 0 * 512 + lane * 8), dA);
      dB = MFMA32(aF[2], ldb(base + t5 * 2048 + 2 * 512 + lane * 8), dB);
      dA = MFMA32(aF[1], ldb(base + t5 * 2048 + 1 * 512 + lane * 8), dA);
      dB = MFMA32(aF[3], ldb(base + t5 * 2048 + 3 * 512 + lane * 8), dB);
#pragma unroll
      for (int r = 0; r < 16; ++r) sum[r] += __builtin_amdgcn_exp2f(dA[r] + dB[r]);
    }
    __builtin_amdgcn_s_setprio(0);
    if (it + 1 < 16) {
      asm volatile("s_waitcnt vmcnt(0)" ::: "memory");
      __builtin_amdgcn_s_barrier();
      cur ^= 1;
    }
  }
  // reduce over cols (l31) -- masks stay within the lh half
#pragma unroll
  for (int m = 1; m < 32; m <<= 1) {
#pragma unroll
    for (int r = 0; r < 16; ++r) sum[r] += __shfl_xor(sum[r], m, 64);
  }
  if (l31 == 0) {
#pragma unroll
    for (int r = 0; r < 16; ++r)
      red[wt][ws][4 * lh + (r & 3) + 8 * (r >> 2)] = sum[r];
  }
  __syncthreads();
  if (tid < 128) {
    int wsi = tid >> 5, row = tid & 31;
    float ssum = red[0][wsi][row] + red[1][wsi][row];
    recip[(long)(b * H_ + h) * S_ + stile * 128 + wsi * 32 + row] = 1.0f / (16.0f * ssum);
  }
}

// ---- pass 2: attn_mean[b,s,t] = sum_h recip[b,h,s]*exp2(score) ----
// grid (16 t-chunks of 128, 16 s-tiles of 128, B) = 512 blocks, block 512 = 8 waves 4s x 2t.
// 32x32x16 MFMA, split-K chains per t5-tile (4 independent 2-deep chains/wave/head).
__global__ __launch_bounds__(512) void k_attn(
    const unsigned short* __restrict__ qsb, const unsigned short* __restrict__ ksb,
    const float* __restrict__ recip, float* __restrict__ am) {
  __shared__ unsigned short lds[16384];         // 2 x 16KB (128t x 64dk, 32-frag-major)
  const int tid = threadIdx.x, wave = tid >> 6, lane = tid & 63;
  const int l31 = lane & 31, lh = lane >> 5;
  const int ws = wave >> 1, wt = wave & 1;
  const int tchunk = blockIdx.x, stile = blockIdx.y, b = blockIdx.z;
  const int s0 = stile * 128 + ws * 32;
  const int t0c = tchunk * 128;

  f16f acc0, acc1;                              // 2 t-tiles of 32 cols each
#pragma unroll
  for (int r = 0; r < 16; ++r) { acc0[r] = 0.f; acc1[r] = 0.f; }

  // A-frag source: Q rows s0+l31, k = k4*16 + lh*8, + h*64 per head
  const unsigned short* qbase = qsb + ((long)(b * S_) + s0 + l31) * D_ + lh * 8;
  // rp rows: s' = (r&3) + 8*(r>>2) + 4*lh -> rpq[j=r>>2] = f4 at s0 + j*8 + 4*lh
  const float* rbase = recip + (long)(b * H_) * S_ + s0 + 4 * lh;

  // staging decode: u = i*512+tid; t31=u&31, khalf=(u>>5)&1, frag=u>>6 (k4=frag&3, t5=frag>>2)
  const int t31s = tid & 31, khs = (tid >> 5) & 1, frs = (tid >> 6) & 7;
  const unsigned short* ga =
      ksb + ((long)(b * S_) + t0c + (frs >> 2) * 32 + t31s) * D_ + (frs & 3) * 16 + khs * 8;

  // prologue: stage head 0 into buf0
  stage16(ga, lds + tid * 8);
  stage16(ga + 64 * D_, lds + 4096 + tid * 8);   // frags 8..15: t5 += 2
  asm volatile("s_waitcnt vmcnt(0)" ::: "memory");
  __builtin_amdgcn_s_barrier();
  int cur = 0;

  for (int h = 0; h < H_; ++h) {
    if (h + 1 < H_) {
      const unsigned short* gn = ga + (h + 1) * 64;
      unsigned short* nb = lds + (cur ^ 1) * 8192;
      stage16(gn, nb + tid * 8);
      stage16(gn + 64 * D_, nb + 4096 + tid * 8);
    }
    bf8 aF[4];
#pragma unroll
    for (int k4 = 0; k4 < 4; ++k4) aF[k4] = ldb(qbase + h * 64 + k4 * 16);
    f4 rpq[4];
#pragma unroll
    for (int j = 0; j < 4; ++j)
      rpq[j] = *reinterpret_cast<const f4*>(rbase + (long)h * S_ + j * 8);
    const unsigned short* base = lds + cur * 8192 + wt * 4096;
    __builtin_amdgcn_s_setprio(1);
    {
      f16f dA, dB;
#pragma unroll
      for (int r = 0; r < 16; ++r) { dA[r] = 0.f; dB[r] = 0.f; }
      dA = MFMA32(aF[0], ldb(base + 0 * 512 + lane * 8), dA);
      dB = MFMA32(aF[2], ldb(base + 2 * 512 + lane * 8), dB);
      dA = MFMA32(aF[1], ldb(base + 1 * 512 + lane * 8), dA);
      dB = MFMA32(aF[3], ldb(base + 3 * 512 + lane * 8), dB);
#pragma unroll
      for (int r = 0; r < 16; ++r)
        acc0[r] += rpq[r >> 2][r & 3] * __builtin_amdgcn_exp2f(dA[r] + dB[r]);
    }
    {
      f16f dA, dB;
#pragma unroll
      for (int r = 0; r < 16; ++r) { dA[r] = 0.f; dB[r] = 0.f; }
      dA = MFMA32(aF[0], ldb(base + 2048 + 0 * 512 + lane * 8), dA);
      dB = MFMA32(aF[2], ldb(base + 2048 + 2 * 512 + lane * 8), dB);
      dA = MFMA32(aF[1], ldb(base + 2048 + 1 * 512 + lane * 8), dA);
      dB = MFMA32(aF[3], ldb(base + 2048 + 3 * 512 + lane * 8), dB);
#pragma unroll
      for (int r = 0; r < 16; ++r)
        acc1[r] += rpq[r >> 2][r & 3] * __builtin_amdgcn_exp2f(dA[r] + dB[r]);
    }
    __builtin_amdgcn_s_setprio(0);
    if (h + 1 < H_) {
      asm volatile("s_waitcnt vmcnt(0)" ::: "memory");
      __builtin_amdgcn_s_barrier();
      cur ^= 1;
    }
  }
  // C layout: row s' = (r&3)+8*(r>>2)+4*lh, col = wt*64 + tile*32 + l31
  float* obase = am + ((long)b * S_ + s0 + 4 * lh) * S_ + t0c + wt * 64 + l31;
#pragma unroll
  for (int r = 0; r < 16; ++r) {
    long ro = (long)((r & 3) + 8 * (r >> 2)) * S_;
    obase[ro] = acc0[r];
    obase[ro + 32] = acc1[r];
  }
}

// ---- head split-K: ph[kc][row][64] f32 = am-chunk @ vs-chunk, kc chunk = 512 t ----
// grid (64 rowgroups, 4 kc), block 256
__global__ __launch_bounds__(256) void k_hpart(
    const float* __restrict__ am, const unsigned short* __restrict__ vst,
    float* __restrict__ ph) {
  const int tid = threadIdx.x, wave = tid >> 6, lane = tid & 63;
  const int l15 = lane & 15, quad = lane >> 4;
  const int rg = blockIdx.x, kc = blockIdx.y;
  const int row0 = rg * 64 + wave * 16;
  const int b = row0 >> 11;
  const float* arow = am + (long)(row0 + l15) * S_ + kc * 512 + quad * 8;
  const unsigned short* vb = vst + (long)b * DK_ * S_ + kc * 512 + quad * 8;
  f4 acc[4];
  for (int i = 0; i < 4; ++i) acc[i] = f4{0.f, 0.f, 0.f, 0.f};
  for (int t0 = 0; t0 < 512; t0 += 32) {
    f4 alo = *reinterpret_cast<const f4*>(arow + t0);
    f4 ahi = *reinterpret_cast<const f4*>(arow + t0 + 4);
    bf8 a = pack_bf8(alo, ahi);
#pragma unroll
    for (int i = 0; i < 4; ++i) {
      bf8 bf = ldb(vb + (long)(i * 16 + l15) * S_ + t0);
      acc[i] = MFMA(a, bf, acc[i]);
    }
  }
#pragma unroll
  for (int i = 0; i < 4; ++i)
#pragma unroll
    for (int r = 0; r < 4; ++r)
      ph[((long)kc * 4096 + row0 + quad * 4 + r) * 64 + i * 16 + l15] = acc[i][r];
}

// reduce -> headb bf16 [row][64] (fully coalesced)
__global__ void k_hred(const float* __restrict__ ph, unsigned short* __restrict__ headb) {
  int e = blockIdx.x * 256 + threadIdx.x;      // e = row*64 + dk
  float s = ph[e] + ph[e + 4096 * 64] + ph[e + 2 * 4096 * 64] + ph[e + 3 * 4096 * 64];
  headb[e] = f2bf_bits(s);
}

// ---- out = head @ Wo ----
// grid (8 d-chunks of 128, 32 s-tiles of 64, B), block 256
__global__ __launch_bounds__(256) void k_out(
    const unsigned short* __restrict__ head, const unsigned short* __restrict__ wot,
    float* __restrict__ out) {
  const int tid = threadIdx.x, wave = tid >> 6, lane = tid & 63;
  const int l15 = lane & 15, quad = lane >> 4;
  const int dchunk = blockIdx.x, stile = blockIdx.y, b = blockIdx.z;
  const int s0 = stile * 64 + wave * 16;
  const int n0 = dchunk * 128;
  const unsigned short* hrow = head + ((long)b * S_ + s0 + l15) * DK_ + quad * 8;
  bf8 a0 = ldb(hrow);
  bf8 a1 = ldb(hrow + 32);
  const unsigned short* wb = wot + quad * 8;
  float* obase = out + ((long)b * S_ + s0 + quad * 4) * D_ + n0 + l15;
#pragma unroll
  for (int i = 0; i < 8; ++i) {
    const unsigned short* wp = wb + (long)(n0 + i * 16 + l15) * DK_;
    bf8 b0 = ldb(wp);
    bf8 b1 = ldb(wp + 32);
    f4 d = f4{0.f, 0.f, 0.f, 0.f};
    d = MFMA(a0, b0, d);
    d = MFMA(a1, b1, d);
#pragma unroll
    for (int r = 0; r < 4; ++r) obase[(long)r * D_ + i * 16] = d[r];
  }
}

extern "C" void kernel_launch(void* const* d_in, const int* in_sizes, int n_in,
                              void* d_out, int out_size, void* d_ws, size_t ws_size,
                              hipStream_t stream) {
  const float* q  = (const float*)d_in[0];
  const float* k  = (const float*)d_in[1];
  const float* v  = (const float*)d_in[2];
  const float* Wq = (const float*)d_in[3];
  const float* Wk = (const float*)d_in[4];
  const float* Wv = (const float*)d_in[5];
  const float* Wo = (const float*)d_in[6];

  float* out = (float*)d_out;                       // [B,S,D] = 4,194,304 f32
  float* am  = out + (long)B_ * S_ * D_;            // [B,S,S] = 8,388,608 f32

  // workspace (~22.5 MB)
  unsigned short* qsb  = (unsigned short*)d_ws;     // [4096][1024]
  unsigned short* ksb  = qsb + 4194304;
  unsigned short* wqt  = ksb + 4194304;             // [1024][1024]
  unsigned short* wkt  = wqt + 1048576;
  unsigned short* wvt  = wkt + 1048576;             // [64][1024]
  unsigned short* wot  = wvt + 65536;               // [1024][64]
  unsigned short* vst  = wot + 65536;               // [B][64][S]
  unsigned short* headb= vst + 262144;              // [4096][64]
  float* recip = (float*)(headb + 262144);          // [B*H*S]

  // bf16 q,k copies live in the am region of d_out (dead before k_attn writes am)
  unsigned short* qb = (unsigned short*)am;         // [4096][1024]
  unsigned short* kb = qb + 4194304;
  // split-K f32 partials [4][4096][64] live in the out region (dead until k_out)
  float* part = out;

  k_prep<<<4384, 256, 0, stream>>>(q, k, Wq, Wk, Wv, Wo, qb, kb, wqt, wkt, wvt, wot);
  k_gemm_qk<<<dim3(32, 8, 2), 256, 0, stream>>>(qb, kb, wqt, wkt, qsb, ksb);
  k_pv<<<dim3(64, 4), 256, 0, stream>>>(v, wvt, part);
  k_vred<<<1024, 256, 0, stream>>>(part, vst);
  k_denom<<<dim3(16, 16, 2), 512, 0, stream>>>(qsb, ksb, recip);
  k_attn<<<dim3(16, 16, 2), 512, 0, stream>>>(qsb, ksb, recip, am);
  k_hpart<<<dim3(64, 4), 256, 0, stream>>>(am, vst, part);
  k_hred<<<1024, 256, 0, stream>>>(part, headb);
  k_out<<<dim3(8, 32, 2), 256, 0, stream>>>(headb, wot, out);
}

// Round 7
// 260.006 us; speedup vs baseline: 1.1025x; 1.1025x over previous
//
#include <hip/hip_runtime.h>

// B=2, S=2048, D=1024, H=16, DK=64
// out = attn_mean @ vs @ Wo  (Wv shared across heads => mean_h(attn_h @ vs) = attn_mean @ vs)
// attn_mean[b,s,t] = (1/H) sum_h exp(score)/denom  -- no max-subtraction (scores bounded ~|2.5|)
// qs/ks layout: [b*S+s][h*64+dk]  (concatenated-head GEMM output)
// All LDS tiles are FRAGMENT-MAJOR: 16B-unit index = tile*64 + quad*16 + l15
//   -> reader addr = tilebase + lane*16B, conflict-free for ds_read_b128.
// k_denom/k_attn (r7): r3 geometry EXACTLY (16x16 MFMA, 512 blocks, 512 thr, 2x16KB dbuf,
// 2-phase staging) but waves re-shaped 4s x 2t: each wave = 32s x 64t, reads only its
// 64-t HALF of the staged tile (8KB/head vs 16KB) via two A-frags per B-frag -> halves
// LDS-read traffic (the r3 busy-time model's dominant term) at unchanged everything-else.
// r4/r5/r6 lessons: fix must hold LDS size (occupancy), chain depth 2 (ILP), VGPR<128.
#define B_ 2
#define S_ 2048
#define D_ 1024
#define H_ 16
#define DK_ 64

typedef __bf16 bf8 __attribute__((ext_vector_type(8)));
typedef float f4 __attribute__((ext_vector_type(4)));
typedef unsigned short u16x8 __attribute__((ext_vector_type(8)));

__device__ __forceinline__ unsigned short f2bf_bits(float f) {
  unsigned int u = __float_as_uint(f);
  return (unsigned short)((u + 0x7fffu + ((u >> 16) & 1u)) >> 16);
}

__device__ __forceinline__ bf8 pack_bf8(f4 lo, f4 hi) {
  u16x8 u;
  u[0] = f2bf_bits(lo[0]); u[1] = f2bf_bits(lo[1]);
  u[2] = f2bf_bits(lo[2]); u[3] = f2bf_bits(lo[3]);
  u[4] = f2bf_bits(hi[0]); u[5] = f2bf_bits(hi[1]);
  u[6] = f2bf_bits(hi[2]); u[7] = f2bf_bits(hi[3]);
  union { u16x8 u; bf8 b; } x; x.u = u; return x.b;
}

__device__ __forceinline__ bf8 ldb(const unsigned short* p) {
  return *reinterpret_cast<const bf8*>(p);
}

__device__ __forceinline__ void stage16(const void* g, void* l) {
  __builtin_amdgcn_global_load_lds(
      (const __attribute__((address_space(1))) void*)g,
      (__attribute__((address_space(3))) void*)l, 16, 0, 0);
}

#define MFMA(a, b, c) __builtin_amdgcn_mfma_f32_16x16x32_bf16((a), (b), (c), 0, 0, 0)

// ---- merged prep: cast q,k -> bf16 rows; LDS-tiled transpose-cast weights ----
// blocks 0..4095: cast q/k | 4096..4351: wq/wk 64x64 tiles | 4352..4367: wv | 4368..4383: wo
__global__ void k_prep(const float* __restrict__ q, const float* __restrict__ k,
                       const float* __restrict__ wq, const float* __restrict__ wk,
                       const float* __restrict__ wv, const float* __restrict__ wo,
                       unsigned short* __restrict__ qb, unsigned short* __restrict__ kb,
                       unsigned short* __restrict__ wqt, unsigned short* __restrict__ wkt,
                       unsigned short* __restrict__ wvt, unsigned short* __restrict__ wot) {
  __shared__ float tl[64 * 65];
  int bid = blockIdx.x, tid = threadIdx.x;
  const int rr = tid >> 6, cc = tid & 63;
  if (bid < 4096) {
    int which = bid >> 11;
    long i = ((long)(bid & 2047) * 256 + tid) * 8;
    const float* src = which ? k : q;
    unsigned short* dst = which ? kb : qb;
    f4 lo = *reinterpret_cast<const f4*>(src + i);
    f4 hi = *reinterpret_cast<const f4*>(src + i + 4);
    *reinterpret_cast<bf8*>(dst + i) = pack_bf8(lo, hi);
  } else if (bid < 4352) {
    // Wq/Wk [h][d][n=dk] -> [h][n][d], 64x64 f32 tile via LDS (coalesced both ways)
    int blk = bid - 4096;
    int h = blk >> 4, d0 = (blk & 15) * 64;
    for (int m = 0; m < 2; ++m) {
      const float* src = m ? wk : wq;
      unsigned short* dst = m ? wkt : wqt;
      if (m) __syncthreads();
#pragma unroll
      for (int it = 0; it < 16; ++it) {
        int d = it * 4 + rr;
        tl[cc * 65 + d] = src[(long)h * 65536 + (d0 + d) * 64 + cc];
      }
      __syncthreads();
#pragma unroll
      for (int it = 0; it < 16; ++it) {
        int n = it * 4 + rr;
        dst[(long)h * 65536 + n * 1024 + d0 + cc] = f2bf_bits(tl[n * 65 + cc]);
      }
    }
  } else if (bid < 4368) {
    // Wv [d][n=dk] -> [n][d]
    int d0 = (bid - 4352) * 64;
#pragma unroll
    for (int it = 0; it < 16; ++it) {
      int d = it * 4 + rr;
      tl[cc * 65 + d] = wv[(long)(d0 + d) * 64 + cc];
    }
    __syncthreads();
#pragma unroll
    for (int it = 0; it < 16; ++it) {
      int n = it * 4 + rr;
      wvt[(long)n * 1024 + d0 + cc] = f2bf_bits(tl[n * 65 + cc]);
    }
  } else {
    // Wo [kk][dd] -> [dd][kk]
    int d0 = (bid - 4368) * 64;
#pragma unroll
    for (int it = 0; it < 16; ++it) {
      int kk = it * 4 + rr;
      tl[cc * 65 + kk] = wo[(long)kk * 1024 + d0 + cc];   // tl[ddl][kk]
    }
    __syncthreads();
#pragma unroll
    for (int it = 0; it < 16; ++it) {
      int ddl = it * 4 + rr;
      wot[(long)(d0 + ddl) * 64 + cc] = f2bf_bits(tl[ddl * 65 + cc]);
    }
  }
}

// ---- GEMM: C[4096][1024] = X @ W^T, 128x128 tile, BK=32, fragment-major LDS (m97 geometry) ----
// grid (32 m-tiles, 8 n-tiles, which), block 256 (4 waves 2x2; wave = 64m x 64n, 4x4 MFMA)
__global__ __launch_bounds__(256) void k_gemm_qk(
    const unsigned short* __restrict__ qb, const unsigned short* __restrict__ kb,
    const unsigned short* __restrict__ wqt, const unsigned short* __restrict__ wkt,
    unsigned short* __restrict__ qsb, unsigned short* __restrict__ ksb) {
  __shared__ unsigned short lds[8192];          // A 8 tiles @0 (tile*512), B 8 tiles @4096
  const int tid = threadIdx.x, wave = tid >> 6, lane = tid & 63;
  const int l15 = lane & 15, quad = lane >> 4;
  const int m0 = blockIdx.x * 128, n0 = blockIdx.y * 128;
  const int which = blockIdx.z;
  const unsigned short* A = which ? kb : qb;
  const unsigned short* W = which ? wkt : wqt;
  unsigned short* C = which ? ksb : qsb;
  const float scale = which ? 1.0f : 0.18033688011112042f;  // log2(e)/8 folded into qs
  const int wr = wave >> 1, wc = wave & 1;

  f4 acc[4][4];
#pragma unroll
  for (int i = 0; i < 4; ++i)
#pragma unroll
    for (int j = 0; j < 4; ++j) acc[i][j] = f4{0.f, 0.f, 0.f, 0.f};

  // staging decode: u = i*256+tid; tile=u>>6 (st + i*4), quad=(u>>4)&3, l15=u&15
  const int sl15 = tid & 15, squad = (tid >> 4) & 3, st = tid >> 6;
  const unsigned short* gA = A + (long)(m0 + st * 16 + sl15) * D_ + squad * 8;
  const unsigned short* gB = W + (long)(n0 + st * 16 + sl15) * D_ + squad * 8;

  for (int k0 = 0; k0 < D_; k0 += 32) {
    stage16(gA + k0, lds + tid * 8);                       // A tiles 0..3
    stage16(gA + 64 * D_ + k0, lds + 2048 + tid * 8);      // A tiles 4..7
    stage16(gB + k0, lds + 4096 + tid * 8);                // B tiles 0..3
    stage16(gB + 64 * D_ + k0, lds + 6144 + tid * 8);      // B tiles 4..7
    __syncthreads();
    bf8 aF[4], bF[4];
#pragma unroll
    for (int mi = 0; mi < 4; ++mi)
      aF[mi] = ldb(lds + (wr * 4 + mi) * 512 + lane * 8);
#pragma unroll
    for (int ni = 0; ni < 4; ++ni)
      bF[ni] = ldb(lds + 4096 + (wc * 4 + ni) * 512 + lane * 8);
#pragma unroll
    for (int mi = 0; mi < 4; ++mi)
#pragma unroll
      for (int ni = 0; ni < 4; ++ni)
        acc[mi][ni] = MFMA(aF[mi], bF[ni], acc[mi][ni]);
    __syncthreads();
  }
#pragma unroll
  for (int mi = 0; mi < 4; ++mi)
#pragma unroll
    for (int r = 0; r < 4; ++r) {
      long row = m0 + wr * 64 + mi * 16 + quad * 4 + r;
#pragma unroll
      for (int ni = 0; ni < 4; ++ni)
        C[row * D_ + n0 + wc * 64 + ni * 16 + l15] = f2bf_bits(acc[mi][ni][r] * scale);
    }
}

// ---- V projection split-K: partial[kc][row][64] f32, kc chunk = 256 ----
// grid (64 rowgroups of 64, 4 kc), block 256
__global__ __launch_bounds__(256) void k_pv(
    const float* __restrict__ v, const unsigned short* __restrict__ wvt,
    float* __restrict__ pv) {
  const int tid = threadIdx.x, wave = tid >> 6, lane = tid & 63;
  const int l15 = lane & 15, quad = lane >> 4;
  const int rg = blockIdx.x, kc = blockIdx.y;
  const int row0 = rg * 64 + wave * 16;
  const float* arow = v + (long)(row0 + l15) * D_ + kc * 256 + quad * 8;
  const unsigned short* wbase = wvt + kc * 256 + quad * 8;
  f4 acc[4];
  for (int i = 0; i < 4; ++i) acc[i] = f4{0.f, 0.f, 0.f, 0.f};
  for (int k0 = 0; k0 < 256; k0 += 32) {
    f4 alo = *reinterpret_cast<const f4*>(arow + k0);
    f4 ahi = *reinterpret_cast<const f4*>(arow + k0 + 4);
    bf8 a = pack_bf8(alo, ahi);
#pragma unroll
    for (int i = 0; i < 4; ++i) {
      bf8 bf = ldb(wbase + (long)(i * 16 + l15) * D_ + k0);
      acc[i] = MFMA(a, bf, acc[i]);
    }
  }
#pragma unroll
  for (int i = 0; i < 4; ++i)
#pragma unroll
    for (int r = 0; r < 4; ++r)
      pv[((long)kc * 4096 + row0 + quad * 4 + r) * 64 + i * 16 + l15] = acc[i][r];
}

// reduce 4 k-partials -> vst[b][dk][t] bf16 (writes coalesced over t)
__global__ void k_vred(const float* __restrict__ pv, unsigned short* __restrict__ vst) {
  int e = blockIdx.x * 256 + threadIdx.x;      // e = (b*64+dk)*2048 + t
  int t = e & 2047, dk = (e >> 11) & 63, b = e >> 17;
  long row = (long)b * S_ + t;
  float s = pv[row * 64 + dk] + pv[(4096 + row) * 64 + dk] +
            pv[(8192 + row) * 64 + dk] + pv[(12288 + row) * 64 + dk];
  vst[e] = f2bf_bits(s);
}

// ---- pass 1: recip[b,h,s] = 1/(H * sum_t exp2(qs.ks)) ----
// grid (16 s-tiles of 128, H, B) = 512 blocks, block 512 = 8 waves, 4s x 2t.
// Wave = 32 s-rows (two A-frags) x 64-t half of each staged 128-t tile -> reads 8KB/tile
// (halved vs r3). Per-wave t-half sums combined at the end via 1KB LDS reduce.
__global__ __launch_bounds__(512) void k_denom(
    const unsigned short* __restrict__ qsb, const unsigned short* __restrict__ ksb,
    float* __restrict__ recip) {
  __shared__ unsigned short lds[16384];         // 2 x (128 t-rows x 64 dk), fragment-major
  __shared__ float red[2][4][32];               // [wt][ws][row 0..31]
  const int tid = threadIdx.x, wave = tid >> 6, lane = tid & 63;
  const int l15 = lane & 15, quad = lane >> 4;
  const int ws = wave >> 1, wt = wave & 1;
  const int stile = blockIdx.x, h = blockIdx.y, b = blockIdx.z;
  const int s0 = stile * 128 + ws * 32;

  const unsigned short* qrow = qsb + ((long)(b * S_) + s0 + l15) * D_ + h * 64 + quad * 8;
  bf8 a0 = ldb(qrow);
  bf8 a1 = ldb(qrow + 32);
  bf8 a2 = ldb(qrow + 16 * D_);
  bf8 a3 = ldb(qrow + 16 * D_ + 32);

  // staging decode (r3): u = i*512+tid; sl15=u&15, squad=(u>>4)&3, stt=(u>>6)&7, sh2=u>>9
  const int sl15 = tid & 15, squad = (tid >> 4) & 3, stt = (tid >> 6) & 7;
  const unsigned short* g0 =
      ksb + ((long)(b * S_) + stt * 16 + sl15) * D_ + h * 64 + squad * 8;

  // prologue: stage tile 0 into buf0
  stage16(g0, lds + tid * 8);
  stage16(g0 + 32, lds + 4096 + tid * 8);
  asm volatile("s_waitcnt vmcnt(0)" ::: "memory");
  __builtin_amdgcn_s_barrier();
  int cur = 0;

  f4 sum0 = f4{0.f, 0.f, 0.f, 0.f}, sum1 = f4{0.f, 0.f, 0.f, 0.f};
  for (int it = 0; it < 16; ++it) {
    if (it + 1 < 16) {
      const unsigned short* gn = g0 + (long)(it + 1) * 128 * D_;
      unsigned short* nb = lds + (cur ^ 1) * 8192;
      stage16(gn, nb + tid * 8);
      stage16(gn + 32, nb + 4096 + tid * 8);
    }
    // wave's t-half: t-frags wt*4 .. wt*4+3 (dk-lo at +0, dk-hi at +4096)
    const unsigned short* base = lds + cur * 8192 + wt * 2048;
    __builtin_amdgcn_s_setprio(1);
#pragma unroll
    for (int tt = 0; tt < 4; ++tt) {
      bf8 b0 = ldb(base + tt * 512 + lane * 8);
      bf8 b1 = ldb(base + 4096 + tt * 512 + lane * 8);
      f4 dA = f4{0.f, 0.f, 0.f, 0.f}, dB = f4{0.f, 0.f, 0.f, 0.f};
      dA = MFMA(a0, b0, dA);
      dB = MFMA(a2, b0, dB);
      dA = MFMA(a1, b1, dA);
      dB = MFMA(a3, b1, dB);
#pragma unroll
      for (int r = 0; r < 4; ++r) {
        sum0[r] += __builtin_amdgcn_exp2f(dA[r]);
        sum1[r] += __builtin_amdgcn_exp2f(dB[r]);
      }
    }
    __builtin_amdgcn_s_setprio(0);
    if (it + 1 < 16) {
      asm volatile("s_waitcnt vmcnt(0)" ::: "memory");
      __builtin_amdgcn_s_barrier();
      cur ^= 1;
    }
  }
  // sum over t-cols (l15) within each 16-lane group
#pragma unroll
  for (int m = 1; m < 16; m <<= 1) {
#pragma unroll
    for (int r = 0; r < 4; ++r) {
      sum0[r] += __shfl_xor(sum0[r], m, 64);
      sum1[r] += __shfl_xor(sum1[r], m, 64);
    }
  }
  if (l15 == 0) {
#pragma unroll
    for (int r = 0; r < 4; ++r) {
      red[wt][ws][quad * 4 + r] = sum0[r];        // s-frag 0 rows
      red[wt][ws][16 + quad * 4 + r] = sum1[r];   // s-frag 1 rows
    }
  }
  __syncthreads();
  if (tid < 128) {
    int wsi = tid >> 5, row = tid & 31;
    float ssum = red[0][wsi][row] + red[1][wsi][row];
    recip[(long)(b * H_ + h) * S_ + stile * 128 + wsi * 32 + row] = 1.0f / (16.0f * ssum);
  }
}

// ---- pass 2: attn_mean[b,s,t] = sum_h recip[b,h,s]*exp2(score) ----
// grid (16 t-chunks of 128, 16 s-tiles of 128, B) = 512 blocks, block 512 = 8 waves 4s x 2t.
// Wave = 32 s-rows x its 64-t half: 8KB LDS read/head (halved vs r3) at r3's exact
// LDS/grid/staging. Two independent 2-deep MFMA chains per tt (dA, dB) preserve ILP.
__global__ __launch_bounds__(512) void k_attn(
    const unsigned short* __restrict__ qsb, const unsigned short* __restrict__ ksb,
    const float* __restrict__ recip, float* __restrict__ am) {
  __shared__ unsigned short lds[16384];         // 2 x (128 t-rows x 64 dk), fragment-major
  const int tid = threadIdx.x, wave = tid >> 6, lane = tid & 63;
  const int l15 = lane & 15, quad = lane >> 4;
  const int ws = wave >> 1, wt = wave & 1;
  const int tchunk = blockIdx.x, stile = blockIdx.y, b = blockIdx.z;
  const int s0 = stile * 128 + ws * 32;
  const int t0c = tchunk * 128;

  f4 acc0[4], acc1[4];
#pragma unroll
  for (int tt = 0; tt < 4; ++tt) {
    acc0[tt] = f4{0.f, 0.f, 0.f, 0.f};
    acc1[tt] = f4{0.f, 0.f, 0.f, 0.f};
  }

  const unsigned short* qbase = qsb + ((long)(b * S_) + s0 + l15) * D_ + quad * 8;
  // staging decode (r3): sl15=tid&15, squad=(tid>>4)&3, stt=(tid>>6)&7
  const int sl15 = tid & 15, squad = (tid >> 4) & 3, stt = (tid >> 6) & 7;
  const unsigned short* g0 =
      ksb + ((long)(b * S_) + t0c + stt * 16 + sl15) * D_ + squad * 8;
  const float* rbase = recip + (long)(b * H_) * S_ + s0 + quad * 4;

  // prologue: stage head 0 into buf0
  stage16(g0, lds + tid * 8);
  stage16(g0 + 32, lds + 4096 + tid * 8);
  asm volatile("s_waitcnt vmcnt(0)" ::: "memory");
  __builtin_amdgcn_s_barrier();
  int cur = 0;

  for (int h = 0; h < H_; ++h) {
    if (h + 1 < H_) {
      const unsigned short* gn = g0 + (h + 1) * 64;
      unsigned short* nb = lds + (cur ^ 1) * 8192;
      stage16(gn, nb + tid * 8);
      stage16(gn + 32, nb + 4096 + tid * 8);
    }
    bf8 a0 = ldb(qbase + h * 64);
    bf8 a1 = ldb(qbase + h * 64 + 32);
    bf8 a2 = ldb(qbase + h * 64 + 16 * D_);
    bf8 a3 = ldb(qbase + h * 64 + 16 * D_ + 32);
    f4 rp0 = *reinterpret_cast<const f4*>(rbase + (long)h * S_);
    f4 rp1 = *reinterpret_cast<const f4*>(rbase + (long)h * S_ + 16);
    // wave's t-half: t-frags wt*4 .. wt*4+3
    const unsigned short* base = lds + cur * 8192 + wt * 2048;
    __builtin_amdgcn_s_setprio(1);
#pragma unroll
    for (int tt = 0; tt < 4; ++tt) {
      bf8 b0 = ldb(base + tt * 512 + lane * 8);
      bf8 b1 = ldb(base + 4096 + tt * 512 + lane * 8);
      f4 dA = f4{0.f, 0.f, 0.f, 0.f}, dB = f4{0.f, 0.f, 0.f, 0.f};
      dA = MFMA(a0, b0, dA);
      dB = MFMA(a2, b0, dB);
      dA = MFMA(a1, b1, dA);
      dB = MFMA(a3, b1, dB);
#pragma unroll
      for (int r = 0; r < 4; ++r) {
        acc0[tt][r] += rp0[r] * __builtin_amdgcn_exp2f(dA[r]);
        acc1[tt][r] += rp1[r] * __builtin_amdgcn_exp2f(dB[r]);
      }
    }
    __builtin_amdgcn_s_setprio(0);
    if (h + 1 < H_) {
      asm volatile("s_waitcnt vmcnt(0)" ::: "memory");
      __builtin_amdgcn_s_barrier();
      cur ^= 1;
    }
  }
  // rows: s0 + sf*16 + quad*4 + r; cols: t0c + wt*64 + tt*16 + l15
  float* obase = am + ((long)b * S_ + s0 + quad * 4) * S_ + t0c + wt * 64 + l15;
#pragma unroll
  for (int tt = 0; tt < 4; ++tt)
#pragma unroll
    for (int r = 0; r < 4; ++r) {
      obase[(long)r * S_ + tt * 16] = acc0[tt][r];
      obase[(long)(16 + r) * S_ + tt * 16] = acc1[tt][r];
    }
}

// ---- head split-K: ph[kc][row][64] f32 = am-chunk @ vs-chunk, kc chunk = 512 t ----
// grid (64 rowgroups, 4 kc), block 256
__global__ __launch_bounds__(256) void k_hpart(
    const float* __restrict__ am, const unsigned short* __restrict__ vst,
    float* __restrict__ ph) {
  const int tid = threadIdx.x, wave = tid >> 6, lane = tid & 63;
  const int l15 = lane & 15, quad = lane >> 4;
  const int rg = blockIdx.x, kc = blockIdx.y;
  const int row0 = rg * 64 + wave * 16;
  const int b = row0 >> 11;
  const float* arow = am + (long)(row0 + l15) * S_ + kc * 512 + quad * 8;
  const unsigned short* vb = vst + (long)b * DK_ * S_ + kc * 512 + quad * 8;
  f4 acc[4];
  for (int i = 0; i < 4; ++i) acc[i] = f4{0.f, 0.f, 0.f, 0.f};
  for (int t0 = 0; t0 < 512; t0 += 32) {
    f4 alo = *reinterpret_cast<const f4*>(arow + t0);
    f4 ahi = *reinterpret_cast<const f4*>(arow + t0 + 4);
    bf8 a = pack_bf8(alo, ahi);
#pragma unroll
    for (int i = 0; i < 4; ++i) {
      bf8 bf = ldb(vb + (long)(i * 16 + l15) * S_ + t0);
      acc[i] = MFMA(a, bf, acc[i]);
    }
  }
#pragma unroll
  for (int i = 0; i < 4; ++i)
#pragma unroll
    for (int r = 0; r < 4; ++r)
      ph[((long)kc * 4096 + row0 + quad * 4 + r) * 64 + i * 16 + l15] = acc[i][r];
}

// reduce -> headb bf16 [row][64] (fully coalesced)
__global__ void k_hred(const float* __restrict__ ph, unsigned short* __restrict__ headb) {
  int e = blockIdx.x * 256 + threadIdx.x;      // e = row*64 + dk
  float s = ph[e] + ph[e + 4096 * 64] + ph[e + 2 * 4096 * 64] + ph[e + 3 * 4096 * 64];
  headb[e] = f2bf_bits(s);
}

// ---- out = head @ Wo ----
// grid (8 d-chunks of 128, 32 s-tiles of 64, B), block 256
__global__ __launch_bounds__(256) void k_out(
    const unsigned short* __restrict__ head, const unsigned short* __restrict__ wot,
    float* __restrict__ out) {
  const int tid = threadIdx.x, wave = tid >> 6, lane = tid & 63;
  const int l15 = lane & 15, quad = lane >> 4;
  const int dchunk = blockIdx.x, stile = blockIdx.y, b = blockIdx.z;
  const int s0 = stile * 64 + wave * 16;
  const int n0 = dchunk * 128;
  const unsigned short* hrow = head + ((long)b * S_ + s0 + l15) * DK_ + quad * 8;
  bf8 a0 = ldb(hrow);
  bf8 a1 = ldb(hrow + 32);
  const unsigned short* wb = wot + quad * 8;
  float* obase = out + ((long)b * S_ + s0 + quad * 4) * D_ + n0 + l15;
#pragma unroll
  for (int i = 0; i < 8; ++i) {
    const unsigned short* wp = wb + (long)(n0 + i * 16 + l15) * DK_;
    bf8 b0 = ldb(wp);
    bf8 b1 = ldb(wp + 32);
    f4 d = f4{0.f, 0.f, 0.f, 0.f};
    d = MFMA(a0, b0, d);
    d = MFMA(a1, b1, d);
#pragma unroll
    for (int r = 0; r < 4; ++r) obase[(long)r * D_ + i * 16] = d[r];
  }
}

extern "C" void kernel_launch(void* const* d_in, const int* in_sizes, int n_in,
                              void* d_out, int out_size, void* d_ws, size_t ws_size,
                              hipStream_t stream) {
  const float* q  = (const float*)d_in[0];
  const float* k  = (const float*)d_in[1];
  const float* v  = (const float*)d_in[2];
  const float* Wq = (const float*)d_in[3];
  const float* Wk = (const float*)d_in[4];
  const float* Wv = (const float*)d_in[5];
  const float* Wo = (const float*)d_in[6];

  float* out = (float*)d_out;                       // [B,S,D] = 4,194,304 f32
  float* am  = out + (long)B_ * S_ * D_;            // [B,S,S] = 8,388,608 f32

  // workspace (~22.5 MB)
  unsigned short* qsb  = (unsigned short*)d_ws;     // [4096][1024]
  unsigned short* ksb  = qsb + 4194304;
  unsigned short* wqt  = ksb + 4194304;             // [1024][1024]
  unsigned short* wkt  = wqt + 1048576;
  unsigned short* wvt  = wkt + 1048576;             // [64][1024]
  unsigned short* wot  = wvt + 65536;               // [1024][64]
  unsigned short* vst  = wot + 65536;               // [B][64][S]
  unsigned short* headb= vst + 262144;              // [4096][64]
  float* recip = (float*)(headb + 262144);          // [B*H*S]

  // bf16 q,k copies live in the am region of d_out (dead before k_attn writes am)
  unsigned short* qb = (unsigned short*)am;         // [4096][1024]
  unsigned short* kb = qb + 4194304;
  // split-K f32 partials [4][4096][64] live in the out region (dead until k_out)
  float* part = out;

  k_prep<<<4384, 256, 0, stream>>>(q, k, Wq, Wk, Wv, Wo, qb, kb, wqt, wkt, wvt, wot);
  k_gemm_qk<<<dim3(32, 8, 2), 256, 0, stream>>>(qb, kb, wqt, wkt, qsb, ksb);
  k_pv<<<dim3(64, 4), 256, 0, stream>>>(v, wvt, part);
  k_vred<<<1024, 256, 0, stream>>>(part, vst);
  k_denom<<<dim3(16, 16, 2), 512, 0, stream>>>(qsb, ksb, recip);
  k_attn<<<dim3(16, 16, 2), 512, 0, stream>>>(qsb, ksb, recip, am);
  k_hpart<<<dim3(64, 4), 256, 0, stream>>>(am, vst, part);
  k_hred<<<1024, 256, 0, stream>>>(part, headb);
  k_out<<<dim3(8, 32, 2), 256, 0, stream>>>(headb, wot, out);
}

// Round 8
// 241.668 us; speedup vs baseline: 1.1861x; 1.0759x over previous
//
#include <hip/hip_runtime.h>

// B=2, S=2048, D=1024, H=16, DK=64
// out = attn_mean @ vs @ Wo  (Wv shared across heads => mean_h(attn_h @ vs) = attn_mean @ vs)
// attn_mean[b,s,t] = (1/H) sum_h exp(score)/denom  -- no max-subtraction (scores bounded ~|2.5|)
// qs/ks layout: [b*S+s][h*64+dk]  (concatenated-head GEMM output)
// All LDS tiles are FRAGMENT-MAJOR: 16B-unit index = tile*64 + quad*16 + l15
//   -> reader addr = tilebase + lane*16B, conflict-free for ds_read_b128.
// r8: r3's exact kernels + XCD-LOCALITY SWIZZLE. Seven-round traffic model: k_attn dur ==
// global-read-bytes / ~6.5 TB/s (L3/fabric ceiling; HBM only 1.2-1.7 TB/s of it). Default
// dispatch scatters consecutive tchunks across XCDs -> every XCD streams all 16MB of
// qsb+ksb through L3. Remap (1D grid, xcd = n&7 round-robin) so each XCD owns an 8x8
// stile x tchunk sub-grid of one batch: working set 8x256KB Q + 8x256KB K = 4MB = L2.
// All 512 blocks co-resident (2/CU) -> assignment is static.
#define B_ 2
#define S_ 2048
#define D_ 1024
#define H_ 16
#define DK_ 64

typedef __bf16 bf8 __attribute__((ext_vector_type(8)));
typedef float f4 __attribute__((ext_vector_type(4)));
typedef unsigned short u16x8 __attribute__((ext_vector_type(8)));

__device__ __forceinline__ unsigned short f2bf_bits(float f) {
  unsigned int u = __float_as_uint(f);
  return (unsigned short)((u + 0x7fffu + ((u >> 16) & 1u)) >> 16);
}

__device__ __forceinline__ bf8 pack_bf8(f4 lo, f4 hi) {
  u16x8 u;
  u[0] = f2bf_bits(lo[0]); u[1] = f2bf_bits(lo[1]);
  u[2] = f2bf_bits(lo[2]); u[3] = f2bf_bits(lo[3]);
  u[4] = f2bf_bits(hi[0]); u[5] = f2bf_bits(hi[1]);
  u[6] = f2bf_bits(hi[2]); u[7] = f2bf_bits(hi[3]);
  union { u16x8 u; bf8 b; } x; x.u = u; return x.b;
}

__device__ __forceinline__ bf8 ldb(const unsigned short* p) {
  return *reinterpret_cast<const bf8*>(p);
}

__device__ __forceinline__ void stage16(const void* g, void* l) {
  __builtin_amdgcn_global_load_lds(
      (const __attribute__((address_space(1))) void*)g,
      (__attribute__((address_space(3))) void*)l, 16, 0, 0);
}

#define MFMA(a, b, c) __builtin_amdgcn_mfma_f32_16x16x32_bf16((a), (b), (c), 0, 0, 0)

// ---- merged prep: cast q,k -> bf16 rows; LDS-tiled transpose-cast weights ----
// blocks 0..4095: cast q/k | 4096..4351: wq/wk 64x64 tiles | 4352..4367: wv | 4368..4383: wo
__global__ void k_prep(const float* __restrict__ q, const float* __restrict__ k,
                       const float* __restrict__ wq, const float* __restrict__ wk,
                       const float* __restrict__ wv, const float* __restrict__ wo,
                       unsigned short* __restrict__ qb, unsigned short* __restrict__ kb,
                       unsigned short* __restrict__ wqt, unsigned short* __restrict__ wkt,
                       unsigned short* __restrict__ wvt, unsigned short* __restrict__ wot) {
  __shared__ float tl[64 * 65];
  int bid = blockIdx.x, tid = threadIdx.x;
  const int rr = tid >> 6, cc = tid & 63;
  if (bid < 4096) {
    int which = bid >> 11;
    long i = ((long)(bid & 2047) * 256 + tid) * 8;
    const float* src = which ? k : q;
    unsigned short* dst = which ? kb : qb;
    f4 lo = *reinterpret_cast<const f4*>(src + i);
    f4 hi = *reinterpret_cast<const f4*>(src + i + 4);
    *reinterpret_cast<bf8*>(dst + i) = pack_bf8(lo, hi);
  } else if (bid < 4352) {
    // Wq/Wk [h][d][n=dk] -> [h][n][d], 64x64 f32 tile via LDS (coalesced both ways)
    int blk = bid - 4096;
    int h = blk >> 4, d0 = (blk & 15) * 64;
    for (int m = 0; m < 2; ++m) {
      const float* src = m ? wk : wq;
      unsigned short* dst = m ? wkt : wqt;
      if (m) __syncthreads();
#pragma unroll
      for (int it = 0; it < 16; ++it) {
        int d = it * 4 + rr;
        tl[cc * 65 + d] = src[(long)h * 65536 + (d0 + d) * 64 + cc];
      }
      __syncthreads();
#pragma unroll
      for (int it = 0; it < 16; ++it) {
        int n = it * 4 + rr;
        dst[(long)h * 65536 + n * 1024 + d0 + cc] = f2bf_bits(tl[n * 65 + cc]);
      }
    }
  } else if (bid < 4368) {
    // Wv [d][n=dk] -> [n][d]
    int d0 = (bid - 4352) * 64;
#pragma unroll
    for (int it = 0; it < 16; ++it) {
      int d = it * 4 + rr;
      tl[cc * 65 + d] = wv[(long)(d0 + d) * 64 + cc];
    }
    __syncthreads();
#pragma unroll
    for (int it = 0; it < 16; ++it) {
      int n = it * 4 + rr;
      wvt[(long)n * 1024 + d0 + cc] = f2bf_bits(tl[n * 65 + cc]);
    }
  } else {
    // Wo [kk][dd] -> [dd][kk]
    int d0 = (bid - 4368) * 64;
#pragma unroll
    for (int it = 0; it < 16; ++it) {
      int kk = it * 4 + rr;
      tl[cc * 65 + kk] = wo[(long)kk * 1024 + d0 + cc];   // tl[ddl][kk]
    }
    __syncthreads();
#pragma unroll
    for (int it = 0; it < 16; ++it) {
      int ddl = it * 4 + rr;
      wot[(long)(d0 + ddl) * 64 + cc] = f2bf_bits(tl[ddl * 65 + cc]);
    }
  }
}

// ---- GEMM: C[4096][1024] = X @ W^T, 128x128 tile, BK=32, fragment-major LDS (m97 geometry) ----
// grid (32 m-tiles, 8 n-tiles, which), block 256 (4 waves 2x2; wave = 64m x 64n, 4x4 MFMA)
__global__ __launch_bounds__(256) void k_gemm_qk(
    const unsigned short* __restrict__ qb, const unsigned short* __restrict__ kb,
    const unsigned short* __restrict__ wqt, const unsigned short* __restrict__ wkt,
    unsigned short* __restrict__ qsb, unsigned short* __restrict__ ksb) {
  __shared__ unsigned short lds[8192];          // A 8 tiles @0 (tile*512), B 8 tiles @4096
  const int tid = threadIdx.x, wave = tid >> 6, lane = tid & 63;
  const int l15 = lane & 15, quad = lane >> 4;
  const int m0 = blockIdx.x * 128, n0 = blockIdx.y * 128;
  const int which = blockIdx.z;
  const unsigned short* A = which ? kb : qb;
  const unsigned short* W = which ? wkt : wqt;
  unsigned short* C = which ? ksb : qsb;
  const float scale = which ? 1.0f : 0.18033688011112042f;  // log2(e)/8 folded into qs
  const int wr = wave >> 1, wc = wave & 1;

  f4 acc[4][4];
#pragma unroll
  for (int i = 0; i < 4; ++i)
#pragma unroll
    for (int j = 0; j < 4; ++j) acc[i][j] = f4{0.f, 0.f, 0.f, 0.f};

  // staging decode: u = i*256+tid; tile=u>>6 (st + i*4), quad=(u>>4)&3, l15=u&15
  const int sl15 = tid & 15, squad = (tid >> 4) & 3, st = tid >> 6;
  const unsigned short* gA = A + (long)(m0 + st * 16 + sl15) * D_ + squad * 8;
  const unsigned short* gB = W + (long)(n0 + st * 16 + sl15) * D_ + squad * 8;

  for (int k0 = 0; k0 < D_; k0 += 32) {
    stage16(gA + k0, lds + tid * 8);                       // A tiles 0..3
    stage16(gA + 64 * D_ + k0, lds + 2048 + tid * 8);      // A tiles 4..7
    stage16(gB + k0, lds + 4096 + tid * 8);                // B tiles 0..3
    stage16(gB + 64 * D_ + k0, lds + 6144 + tid * 8);      // B tiles 4..7
    __syncthreads();
    bf8 aF[4], bF[4];
#pragma unroll
    for (int mi = 0; mi < 4; ++mi)
      aF[mi] = ldb(lds + (wr * 4 + mi) * 512 + lane * 8);
#pragma unroll
    for (int ni = 0; ni < 4; ++ni)
      bF[ni] = ldb(lds + 4096 + (wc * 4 + ni) * 512 + lane * 8);
#pragma unroll
    for (int mi = 0; mi < 4; ++mi)
#pragma unroll
      for (int ni = 0; ni < 4; ++ni)
        acc[mi][ni] = MFMA(aF[mi], bF[ni], acc[mi][ni]);
    __syncthreads();
  }
#pragma unroll
  for (int mi = 0; mi < 4; ++mi)
#pragma unroll
    for (int r = 0; r < 4; ++r) {
      long row = m0 + wr * 64 + mi * 16 + quad * 4 + r;
#pragma unroll
      for (int ni = 0; ni < 4; ++ni)
        C[row * D_ + n0 + wc * 64 + ni * 16 + l15] = f2bf_bits(acc[mi][ni][r] * scale);
    }
}

// ---- V projection split-K: partial[kc][row][64] f32, kc chunk = 256 ----
// grid (64 rowgroups of 64, 4 kc), block 256
__global__ __launch_bounds__(256) void k_pv(
    const float* __restrict__ v, const unsigned short* __restrict__ wvt,
    float* __restrict__ pv) {
  const int tid = threadIdx.x, wave = tid >> 6, lane = tid & 63;
  const int l15 = lane & 15, quad = lane >> 4;
  const int rg = blockIdx.x, kc = blockIdx.y;
  const int row0 = rg * 64 + wave * 16;
  const float* arow = v + (long)(row0 + l15) * D_ + kc * 256 + quad * 8;
  const unsigned short* wbase = wvt + kc * 256 + quad * 8;
  f4 acc[4];
  for (int i = 0; i < 4; ++i) acc[i] = f4{0.f, 0.f, 0.f, 0.f};
  for (int k0 = 0; k0 < 256; k0 += 32) {
    f4 alo = *reinterpret_cast<const f4*>(arow + k0);
    f4 ahi = *reinterpret_cast<const f4*>(arow + k0 + 4);
    bf8 a = pack_bf8(alo, ahi);
#pragma unroll
    for (int i = 0; i < 4; ++i) {
      bf8 bf = ldb(wbase + (long)(i * 16 + l15) * D_ + k0);
      acc[i] = MFMA(a, bf, acc[i]);
    }
  }
#pragma unroll
  for (int i = 0; i < 4; ++i)
#pragma unroll
    for (int r = 0; r < 4; ++r)
      pv[((long)kc * 4096 + row0 + quad * 4 + r) * 64 + i * 16 + l15] = acc[i][r];
}

// reduce 4 k-partials -> vst[b][dk][t] bf16 (writes coalesced over t)
__global__ void k_vred(const float* __restrict__ pv, unsigned short* __restrict__ vst) {
  int e = blockIdx.x * 256 + threadIdx.x;      // e = (b*64+dk)*2048 + t
  int t = e & 2047, dk = (e >> 11) & 63, b = e >> 17;
  long row = (long)b * S_ + t;
  float s = pv[row * 64 + dk] + pv[(4096 + row) * 64 + dk] +
            pv[(8192 + row) * 64 + dk] + pv[(12288 + row) * 64 + dk];
  vst[e] = f2bf_bits(s);
}

// ---- pass 1: recip[b,h,s] = 1/(H * sum_t exp2(qs.ks)) ----
// 1D grid 512, block 512 (8 waves); XCD-swizzled decode: xcd = n&7 (dispatch round-robin),
// b = xcd>>2, h-group = xcd&3 -> each XCD reads 4 K-columns (1MB) + their Q (1MB) = 2MB in L2.
// Inner structure = r3 exactly: 2-phase dbuf staging, vmcnt(0)+s_barrier per tile, setprio.
__global__ __launch_bounds__(512) void k_denom(
    const unsigned short* __restrict__ qsb, const unsigned short* __restrict__ ksb,
    float* __restrict__ recip) {
  __shared__ unsigned short lds[16384];         // 2 x (128 t-rows x 64 dk), fragment-major
  const int tid = threadIdx.x, wave = tid >> 6, lane = tid & 63;
  const int l15 = lane & 15, quad = lane >> 4;
  const int n = blockIdx.x, xcd = n & 7, slot = n >> 3;
  const int b = xcd >> 2;
  const int h = ((xcd & 3) << 2) | (slot & 3);
  const int stile = slot >> 2;
  const int s0 = stile * 128 + wave * 16;

  const unsigned short* qrow = qsb + ((long)(b * S_) + s0 + l15) * D_ + h * 64 + quad * 8;
  bf8 a0 = ldb(qrow);
  bf8 a1 = ldb(qrow + 32);

  // staging decode for u = tid (sh2=0) and u = tid+512 (sh2=1): stt=(tid>>6)&7
  const int sl15 = tid & 15, squad = (tid >> 4) & 3, stt = (tid >> 6) & 7;
  const unsigned short* g0 =
      ksb + ((long)(b * S_) + stt * 16 + sl15) * D_ + h * 64 + squad * 8;

  // prologue: stage tile 0 into buf0
  stage16(g0, lds + tid * 8);
  stage16(g0 + 32, lds + 4096 + tid * 8);
  asm volatile("s_waitcnt vmcnt(0)" ::: "memory");
  __builtin_amdgcn_s_barrier();
  int cur = 0;

  f4 sum = f4{0.f, 0.f, 0.f, 0.f};
  for (int it = 0; it < 16; ++it) {
    if (it + 1 < 16) {
      const unsigned short* gn = g0 + (long)(it + 1) * 128 * D_;
      unsigned short* nb = lds + (cur ^ 1) * 8192;
      stage16(gn, nb + tid * 8);
      stage16(gn + 32, nb + 4096 + tid * 8);
    }
    const unsigned short* base = lds + cur * 8192;
    __builtin_amdgcn_s_setprio(1);
#pragma unroll
    for (int tt = 0; tt < 8; ++tt) {
      bf8 b0 = ldb(base + tt * 512 + lane * 8);
      bf8 b1 = ldb(base + 4096 + tt * 512 + lane * 8);
      f4 d = f4{0.f, 0.f, 0.f, 0.f};
      d = MFMA(a0, b0, d);
      d = MFMA(a1, b1, d);
#pragma unroll
      for (int r = 0; r < 4; ++r) sum[r] += __builtin_amdgcn_exp2f(d[r]);
    }
    __builtin_amdgcn_s_setprio(0);
    if (it + 1 < 16) {
      asm volatile("s_waitcnt vmcnt(0)" ::: "memory");
      __builtin_amdgcn_s_barrier();
      cur ^= 1;
    }
  }
#pragma unroll
  for (int m = 1; m < 16; m <<= 1) {
#pragma unroll
    for (int r = 0; r < 4; ++r) sum[r] += __shfl_xor(sum[r], m, 64);
  }
  if (l15 == 0) {
    float* rp = recip + (long)(b * H_ + h) * S_ + s0 + quad * 4;
#pragma unroll
    for (int r = 0; r < 4; ++r) rp[r] = 1.0f / (16.0f * sum[r]);
  }
}

// ---- pass 2: attn_mean[b,s,t] = sum_h recip[b,h,s]*exp2(score) ----
// 1D grid 512, block 512 (8 waves); XCD-swizzled decode: each XCD owns an 8x8
// stile x tchunk sub-grid of one batch -> per-XCD working set 8x256KB Q + 8x256KB K
// = 4MB = one L2 (all 512 blocks co-resident at 2/CU, so assignment is static).
// Inner structure = r3 exactly (best measured: 42.1 us).
__global__ __launch_bounds__(512) void k_attn(
    const unsigned short* __restrict__ qsb, const unsigned short* __restrict__ ksb,
    const float* __restrict__ recip, float* __restrict__ am) {
  __shared__ unsigned short lds[16384];         // 2 x (128 t-rows x 64 dk) per head
  const int tid = threadIdx.x, wave = tid >> 6, lane = tid & 63;
  const int l15 = lane & 15, quad = lane >> 4;
  const int n = blockIdx.x, xcd = n & 7, slot = n >> 3;
  const int b = xcd >> 2;
  const int tchunk = ((xcd & 1) << 3) | (slot & 7);
  const int stile = (((xcd >> 1) & 1) << 3) | (slot >> 3);
  const int s0 = stile * 128 + wave * 16;
  const int t0c = tchunk * 128;

  f4 acc[8];
#pragma unroll
  for (int tt = 0; tt < 8; ++tt) acc[tt] = f4{0.f, 0.f, 0.f, 0.f};

  const unsigned short* qbase = qsb + ((long)(b * S_) + s0 + l15) * D_ + quad * 8;
  // staging decode for u = tid (sh2=0) and u = tid+512 (sh2=1): stt=(tid>>6)&7
  const int sl15 = tid & 15, squad = (tid >> 4) & 3, stt = (tid >> 6) & 7;
  const unsigned short* g0 =
      ksb + ((long)(b * S_) + t0c + stt * 16 + sl15) * D_ + squad * 8;
  const float* rbase = recip + (long)(b * H_) * S_ + s0 + quad * 4;

  // prologue: stage head 0 into buf0
  stage16(g0, lds + tid * 8);
  stage16(g0 + 32, lds + 4096 + tid * 8);
  asm volatile("s_waitcnt vmcnt(0)" ::: "memory");
  __builtin_amdgcn_s_barrier();
  int cur = 0;

  for (int h = 0; h < H_; ++h) {
    if (h + 1 < H_) {
      const unsigned short* gn = g0 + (h + 1) * 64;
      unsigned short* nb = lds + (cur ^ 1) * 8192;
      stage16(gn, nb + tid * 8);
      stage16(gn + 32, nb + 4096 + tid * 8);
    }
    bf8 a0 = ldb(qbase + h * 64);
    bf8 a1 = ldb(qbase + h * 64 + 32);
    f4 rp = *reinterpret_cast<const f4*>(rbase + (long)h * S_);
    const unsigned short* base = lds + cur * 8192;
    __builtin_amdgcn_s_setprio(1);
#pragma unroll
    for (int tt = 0; tt < 8; ++tt) {
      bf8 b0 = ldb(base + tt * 512 + lane * 8);
      bf8 b1 = ldb(base + 4096 + tt * 512 + lane * 8);
      f4 d = f4{0.f, 0.f, 0.f, 0.f};
      d = MFMA(a0, b0, d);
      d = MFMA(a1, b1, d);
#pragma unroll
      for (int r = 0; r < 4; ++r) acc[tt][r] += rp[r] * __builtin_amdgcn_exp2f(d[r]);
    }
    __builtin_amdgcn_s_setprio(0);
    if (h + 1 < H_) {
      asm volatile("s_waitcnt vmcnt(0)" ::: "memory");
      __builtin_amdgcn_s_barrier();
      cur ^= 1;
    }
  }
  float* obase = am + ((long)b * S_ + s0 + quad * 4) * S_ + t0c + l15;
#pragma unroll
  for (int tt = 0; tt < 8; ++tt)
#pragma unroll
    for (int r = 0; r < 4; ++r) obase[(long)r * S_ + tt * 16] = acc[tt][r];
}

// ---- head split-K: ph[kc][row][64] f32 = am-chunk @ vs-chunk, kc chunk = 512 t ----
// grid (64 rowgroups, 4 kc), block 256
__global__ __launch_bounds__(256) void k_hpart(
    const float* __restrict__ am, const unsigned short* __restrict__ vst,
    float* __restrict__ ph) {
  const int tid = threadIdx.x, wave = tid >> 6, lane = tid & 63;
  const int l15 = lane & 15, quad = lane >> 4;
  const int rg = blockIdx.x, kc = blockIdx.y;
  const int row0 = rg * 64 + wave * 16;
  const int b = row0 >> 11;
  const float* arow = am + (long)(row0 + l15) * S_ + kc * 512 + quad * 8;
  const unsigned short* vb = vst + (long)b * DK_ * S_ + kc * 512 + quad * 8;
  f4 acc[4];
  for (int i = 0; i < 4; ++i) acc[i] = f4{0.f, 0.f, 0.f, 0.f};
  for (int t0 = 0; t0 < 512; t0 += 32) {
    f4 alo = *reinterpret_cast<const f4*>(arow + t0);
    f4 ahi = *reinterpret_cast<const f4*>(arow + t0 + 4);
    bf8 a = pack_bf8(alo, ahi);
#pragma unroll
    for (int i = 0; i < 4; ++i) {
      bf8 bf = ldb(vb + (long)(i * 16 + l15) * S_ + t0);
      acc[i] = MFMA(a, bf, acc[i]);
    }
  }
#pragma unroll
  for (int i = 0; i < 4; ++i)
#pragma unroll
    for (int r = 0; r < 4; ++r)
      ph[((long)kc * 4096 + row0 + quad * 4 + r) * 64 + i * 16 + l15] = acc[i][r];
}

// reduce -> headb bf16 [row][64] (fully coalesced)
__global__ void k_hred(const float* __restrict__ ph, unsigned short* __restrict__ headb) {
  int e = blockIdx.x * 256 + threadIdx.x;      // e = row*64 + dk
  float s = ph[e] + ph[e + 4096 * 64] + ph[e + 2 * 4096 * 64] + ph[e + 3 * 4096 * 64];
  headb[e] = f2bf_bits(s);
}

// ---- out = head @ Wo ----
// grid (8 d-chunks of 128, 32 s-tiles of 64, B), block 256
__global__ __launch_bounds__(256) void k_out(
    const unsigned short* __restrict__ head, const unsigned short* __restrict__ wot,
    float* __restrict__ out) {
  const int tid = threadIdx.x, wave = tid >> 6, lane = tid & 63;
  const int l15 = lane & 15, quad = lane >> 4;
  const int dchunk = blockIdx.x, stile = blockIdx.y, b = blockIdx.z;
  const int s0 = stile * 64 + wave * 16;
  const int n0 = dchunk * 128;
  const unsigned short* hrow = head + ((long)b * S_ + s0 + l15) * DK_ + quad * 8;
  bf8 a0 = ldb(hrow);
  bf8 a1 = ldb(hrow + 32);
  const unsigned short* wb = wot + quad * 8;
  float* obase = out + ((long)b * S_ + s0 + quad * 4) * D_ + n0 + l15;
#pragma unroll
  for (int i = 0; i < 8; ++i) {
    const unsigned short* wp = wb + (long)(n0 + i * 16 + l15) * DK_;
    bf8 b0 = ldb(wp);
    bf8 b1 = ldb(wp + 32);
    f4 d = f4{0.f, 0.f, 0.f, 0.f};
    d = MFMA(a0, b0, d);
    d = MFMA(a1, b1, d);
#pragma unroll
    for (int r = 0; r < 4; ++r) obase[(long)r * D_ + i * 16] = d[r];
  }
}

extern "C" void kernel_launch(void* const* d_in, const int* in_sizes, int n_in,
                              void* d_out, int out_size, void* d_ws, size_t ws_size,
                              hipStream_t stream) {
  const float* q  = (const float*)d_in[0];
  const float* k  = (const float*)d_in[1];
  const float* v  = (const float*)d_in[2];
  const float* Wq = (const float*)d_in[3];
  const float* Wk = (const float*)d_in[4];
  const float* Wv = (const float*)d_in[5];
  const float* Wo = (const float*)d_in[6];

  float* out = (float*)d_out;                       // [B,S,D] = 4,194,304 f32
  float* am  = out + (long)B_ * S_ * D_;            // [B,S,S] = 8,388,608 f32

  // workspace (~22.5 MB)
  unsigned short* qsb  = (unsigned short*)d_ws;     // [4096][1024]
  unsigned short* ksb  = qsb + 4194304;
  unsigned short* wqt  = ksb + 4194304;             // [1024][1024]
  unsigned short* wkt  = wqt + 1048576;
  unsigned short* wvt  = wkt + 1048576;             // [64][1024]
  unsigned short* wot  = wvt + 65536;               // [1024][64]
  unsigned short* vst  = wot + 65536;               // [B][64][S]
  unsigned short* headb= vst + 262144;              // [4096][64]
  float* recip = (float*)(headb + 262144);          // [B*H*S]

  // bf16 q,k copies live in the am region of d_out (dead before k_attn writes am)
  unsigned short* qb = (unsigned short*)am;         // [4096][1024]
  unsigned short* kb = qb + 4194304;
  // split-K f32 partials [4][4096][64] live in the out region (dead until k_out)
  float* part = out;

  k_prep<<<4384, 256, 0, stream>>>(q, k, Wq, Wk, Wv, Wo, qb, kb, wqt, wkt, wvt, wot);
  k_gemm_qk<<<dim3(32, 8, 2), 256, 0, stream>>>(qb, kb, wqt, wkt, qsb, ksb);
  k_pv<<<dim3(64, 4), 256, 0, stream>>>(v, wvt, part);
  k_vred<<<1024, 256, 0, stream>>>(part, vst);
  k_denom<<<512, 512, 0, stream>>>(qsb, ksb, recip);
  k_attn<<<512, 512, 0, stream>>>(qsb, ksb, recip, am);
  k_hpart<<<dim3(64, 4), 256, 0, stream>>>(am, vst, part);
  k_hred<<<1024, 256, 0, stream>>>(part, headb);
  k_out<<<dim3(8, 32, 2), 256, 0, stream>>>(headb, wot, out);
}

// Round 9
// 239.992 us; speedup vs baseline: 1.1944x; 1.0070x over previous
//
#include <hip/hip_runtime.h>

// B=2, S=2048, D=1024, H=16, DK=64
// out = attn_mean @ vs @ Wo  (Wv shared across heads => mean_h(attn_h @ vs) = attn_mean @ vs)
// attn_mean[b,s,t] = (1/H) sum_h exp(score)/denom  -- no max-subtraction (scores bounded ~|2.5|)
// qs/ks layout: [b*S+s][h*64+dk]  (concatenated-head GEMM output)
// All LDS tiles are FRAGMENT-MAJOR: 16B-unit index = tile*64 + quad*16 + l15
//   -> reader addr = tilebase + lane*16B, conflict-free for ds_read_b128.
// r8: XCD swizzle (FETCH 37.9->16.7 MB, kept). r9: Q-frag REGISTER PIPELINING in k_attn.
// Defect found in r3/r8: per-iteration issue order was [stage16 x2, ldb a0/a1, rp]; vmcnt
// is IN-ORDER, so the wait before the first MFMA (needs a0) could only satisfy after the
// earlier-issued 16KB staging returned -> compute of head h serialized on staging of h+1,
// ~16 serial staging round-trips/block. Fix: load h+1's a0n/a1n/rpn BEFORE its stage16
// (sched_barrier pins order), consume preloaded regs in compute, rotate after barrier.
#define B_ 2
#define S_ 2048
#define D_ 1024
#define H_ 16
#define DK_ 64

typedef __bf16 bf8 __attribute__((ext_vector_type(8)));
typedef float f4 __attribute__((ext_vector_type(4)));
typedef unsigned short u16x8 __attribute__((ext_vector_type(8)));

__device__ __forceinline__ unsigned short f2bf_bits(float f) {
  unsigned int u = __float_as_uint(f);
  return (unsigned short)((u + 0x7fffu + ((u >> 16) & 1u)) >> 16);
}

__device__ __forceinline__ bf8 pack_bf8(f4 lo, f4 hi) {
  u16x8 u;
  u[0] = f2bf_bits(lo[0]); u[1] = f2bf_bits(lo[1]);
  u[2] = f2bf_bits(lo[2]); u[3] = f2bf_bits(lo[3]);
  u[4] = f2bf_bits(hi[0]); u[5] = f2bf_bits(hi[1]);
  u[6] = f2bf_bits(hi[2]); u[7] = f2bf_bits(hi[3]);
  union { u16x8 u; bf8 b; } x; x.u = u; return x.b;
}

__device__ __forceinline__ bf8 ldb(const unsigned short* p) {
  return *reinterpret_cast<const bf8*>(p);
}

__device__ __forceinline__ void stage16(const void* g, void* l) {
  __builtin_amdgcn_global_load_lds(
      (const __attribute__((address_space(1))) void*)g,
      (__attribute__((address_space(3))) void*)l, 16, 0, 0);
}

#define MFMA(a, b, c) __builtin_amdgcn_mfma_f32_16x16x32_bf16((a), (b), (c), 0, 0, 0)

// ---- merged prep: cast q,k -> bf16 rows; LDS-tiled transpose-cast weights ----
// blocks 0..4095: cast q/k | 4096..4351: wq/wk 64x64 tiles | 4352..4367: wv | 4368..4383: wo
__global__ void k_prep(const float* __restrict__ q, const float* __restrict__ k,
                       const float* __restrict__ wq, const float* __restrict__ wk,
                       const float* __restrict__ wv, const float* __restrict__ wo,
                       unsigned short* __restrict__ qb, unsigned short* __restrict__ kb,
                       unsigned short* __restrict__ wqt, unsigned short* __restrict__ wkt,
                       unsigned short* __restrict__ wvt, unsigned short* __restrict__ wot) {
  __shared__ float tl[64 * 65];
  int bid = blockIdx.x, tid = threadIdx.x;
  const int rr = tid >> 6, cc = tid & 63;
  if (bid < 4096) {
    int which = bid >> 11;
    long i = ((long)(bid & 2047) * 256 + tid) * 8;
    const float* src = which ? k : q;
    unsigned short* dst = which ? kb : qb;
    f4 lo = *reinterpret_cast<const f4*>(src + i);
    f4 hi = *reinterpret_cast<const f4*>(src + i + 4);
    *reinterpret_cast<bf8*>(dst + i) = pack_bf8(lo, hi);
  } else if (bid < 4352) {
    // Wq/Wk [h][d][n=dk] -> [h][n][d], 64x64 f32 tile via LDS (coalesced both ways)
    int blk = bid - 4096;
    int h = blk >> 4, d0 = (blk & 15) * 64;
    for (int m = 0; m < 2; ++m) {
      const float* src = m ? wk : wq;
      unsigned short* dst = m ? wkt : wqt;
      if (m) __syncthreads();
#pragma unroll
      for (int it = 0; it < 16; ++it) {
        int d = it * 4 + rr;
        tl[cc * 65 + d] = src[(long)h * 65536 + (d0 + d) * 64 + cc];
      }
      __syncthreads();
#pragma unroll
      for (int it = 0; it < 16; ++it) {
        int n = it * 4 + rr;
        dst[(long)h * 65536 + n * 1024 + d0 + cc] = f2bf_bits(tl[n * 65 + cc]);
      }
    }
  } else if (bid < 4368) {
    // Wv [d][n=dk] -> [n][d]
    int d0 = (bid - 4352) * 64;
#pragma unroll
    for (int it = 0; it < 16; ++it) {
      int d = it * 4 + rr;
      tl[cc * 65 + d] = wv[(long)(d0 + d) * 64 + cc];
    }
    __syncthreads();
#pragma unroll
    for (int it = 0; it < 16; ++it) {
      int n = it * 4 + rr;
      wvt[(long)n * 1024 + d0 + cc] = f2bf_bits(tl[n * 65 + cc]);
    }
  } else {
    // Wo [kk][dd] -> [dd][kk]
    int d0 = (bid - 4368) * 64;
#pragma unroll
    for (int it = 0; it < 16; ++it) {
      int kk = it * 4 + rr;
      tl[cc * 65 + kk] = wo[(long)kk * 1024 + d0 + cc];   // tl[ddl][kk]
    }
    __syncthreads();
#pragma unroll
    for (int it = 0; it < 16; ++it) {
      int ddl = it * 4 + rr;
      wot[(long)(d0 + ddl) * 64 + cc] = f2bf_bits(tl[ddl * 65 + cc]);
    }
  }
}

// ---- GEMM: C[4096][1024] = X @ W^T, 128x128 tile, BK=32, fragment-major LDS (m97 geometry) ----
// grid (32 m-tiles, 8 n-tiles, which), block 256 (4 waves 2x2; wave = 64m x 64n, 4x4 MFMA)
__global__ __launch_bounds__(256) void k_gemm_qk(
    const unsigned short* __restrict__ qb, const unsigned short* __restrict__ kb,
    const unsigned short* __restrict__ wqt, const unsigned short* __restrict__ wkt,
    unsigned short* __restrict__ qsb, unsigned short* __restrict__ ksb) {
  __shared__ unsigned short lds[8192];          // A 8 tiles @0 (tile*512), B 8 tiles @4096
  const int tid = threadIdx.x, wave = tid >> 6, lane = tid & 63;
  const int l15 = lane & 15, quad = lane >> 4;
  const int m0 = blockIdx.x * 128, n0 = blockIdx.y * 128;
  const int which = blockIdx.z;
  const unsigned short* A = which ? kb : qb;
  const unsigned short* W = which ? wkt : wqt;
  unsigned short* C = which ? ksb : qsb;
  const float scale = which ? 1.0f : 0.18033688011112042f;  // log2(e)/8 folded into qs
  const int wr = wave >> 1, wc = wave & 1;

  f4 acc[4][4];
#pragma unroll
  for (int i = 0; i < 4; ++i)
#pragma unroll
    for (int j = 0; j < 4; ++j) acc[i][j] = f4{0.f, 0.f, 0.f, 0.f};

  // staging decode: u = i*256+tid; tile=u>>6 (st + i*4), quad=(u>>4)&3, l15=u&15
  const int sl15 = tid & 15, squad = (tid >> 4) & 3, st = tid >> 6;
  const unsigned short* gA = A + (long)(m0 + st * 16 + sl15) * D_ + squad * 8;
  const unsigned short* gB = W + (long)(n0 + st * 16 + sl15) * D_ + squad * 8;

  for (int k0 = 0; k0 < D_; k0 += 32) {
    stage16(gA + k0, lds + tid * 8);                       // A tiles 0..3
    stage16(gA + 64 * D_ + k0, lds + 2048 + tid * 8);      // A tiles 4..7
    stage16(gB + k0, lds + 4096 + tid * 8);                // B tiles 0..3
    stage16(gB + 64 * D_ + k0, lds + 6144 + tid * 8);      // B tiles 4..7
    __syncthreads();
    bf8 aF[4], bF[4];
#pragma unroll
    for (int mi = 0; mi < 4; ++mi)
      aF[mi] = ldb(lds + (wr * 4 + mi) * 512 + lane * 8);
#pragma unroll
    for (int ni = 0; ni < 4; ++ni)
      bF[ni] = ldb(lds + 4096 + (wc * 4 + ni) * 512 + lane * 8);
#pragma unroll
    for (int mi = 0; mi < 4; ++mi)
#pragma unroll
      for (int ni = 0; ni < 4; ++ni)
        acc[mi][ni] = MFMA(aF[mi], bF[ni], acc[mi][ni]);
    __syncthreads();
  }
#pragma unroll
  for (int mi = 0; mi < 4; ++mi)
#pragma unroll
    for (int r = 0; r < 4; ++r) {
      long row = m0 + wr * 64 + mi * 16 + quad * 4 + r;
#pragma unroll
      for (int ni = 0; ni < 4; ++ni)
        C[row * D_ + n0 + wc * 64 + ni * 16 + l15] = f2bf_bits(acc[mi][ni][r] * scale);
    }
}

// ---- V projection split-K: partial[kc][row][64] f32, kc chunk = 256 ----
// grid (64 rowgroups of 64, 4 kc), block 256
__global__ __launch_bounds__(256) void k_pv(
    const float* __restrict__ v, const unsigned short* __restrict__ wvt,
    float* __restrict__ pv) {
  const int tid = threadIdx.x, wave = tid >> 6, lane = tid & 63;
  const int l15 = lane & 15, quad = lane >> 4;
  const int rg = blockIdx.x, kc = blockIdx.y;
  const int row0 = rg * 64 + wave * 16;
  const float* arow = v + (long)(row0 + l15) * D_ + kc * 256 + quad * 8;
  const unsigned short* wbase = wvt + kc * 256 + quad * 8;
  f4 acc[4];
  for (int i = 0; i < 4; ++i) acc[i] = f4{0.f, 0.f, 0.f, 0.f};
  for (int k0 = 0; k0 < 256; k0 += 32) {
    f4 alo = *reinterpret_cast<const f4*>(arow + k0);
    f4 ahi = *reinterpret_cast<const f4*>(arow + k0 + 4);
    bf8 a = pack_bf8(alo, ahi);
#pragma unroll
    for (int i = 0; i < 4; ++i) {
      bf8 bf = ldb(wbase + (long)(i * 16 + l15) * D_ + k0);
      acc[i] = MFMA(a, bf, acc[i]);
    }
  }
#pragma unroll
  for (int i = 0; i < 4; ++i)
#pragma unroll
    for (int r = 0; r < 4; ++r)
      pv[((long)kc * 4096 + row0 + quad * 4 + r) * 64 + i * 16 + l15] = acc[i][r];
}

// reduce 4 k-partials -> vst[b][dk][t] bf16 (writes coalesced over t)
__global__ void k_vred(const float* __restrict__ pv, unsigned short* __restrict__ vst) {
  int e = blockIdx.x * 256 + threadIdx.x;      // e = (b*64+dk)*2048 + t
  int t = e & 2047, dk = (e >> 11) & 63, b = e >> 17;
  long row = (long)b * S_ + t;
  float s = pv[row * 64 + dk] + pv[(4096 + row) * 64 + dk] +
            pv[(8192 + row) * 64 + dk] + pv[(12288 + row) * 64 + dk];
  vst[e] = f2bf_bits(s);
}

// ---- pass 1: recip[b,h,s] = 1/(H * sum_t exp2(qs.ks)) ----
// 1D grid 512, block 512 (8 waves); XCD-swizzled decode (r8). Q-frags hoisted to prologue
// (already free of the in-order-vmcnt defect). 2-phase dbuf staging, setprio.
__global__ __launch_bounds__(512) void k_denom(
    const unsigned short* __restrict__ qsb, const unsigned short* __restrict__ ksb,
    float* __restrict__ recip) {
  __shared__ unsigned short lds[16384];         // 2 x (128 t-rows x 64 dk), fragment-major
  const int tid = threadIdx.x, wave = tid >> 6, lane = tid & 63;
  const int l15 = lane & 15, quad = lane >> 4;
  const int n = blockIdx.x, xcd = n & 7, slot = n >> 3;
  const int b = xcd >> 2;
  const int h = ((xcd & 3) << 2) | (slot & 3);
  const int stile = slot >> 2;
  const int s0 = stile * 128 + wave * 16;

  const unsigned short* qrow = qsb + ((long)(b * S_) + s0 + l15) * D_ + h * 64 + quad * 8;
  bf8 a0 = ldb(qrow);
  bf8 a1 = ldb(qrow + 32);

  // staging decode for u = tid (sh2=0) and u = tid+512 (sh2=1): stt=(tid>>6)&7
  const int sl15 = tid & 15, squad = (tid >> 4) & 3, stt = (tid >> 6) & 7;
  const unsigned short* g0 =
      ksb + ((long)(b * S_) + stt * 16 + sl15) * D_ + h * 64 + squad * 8;

  // prologue: stage tile 0 into buf0
  stage16(g0, lds + tid * 8);
  stage16(g0 + 32, lds + 4096 + tid * 8);
  asm volatile("s_waitcnt vmcnt(0)" ::: "memory");
  __builtin_amdgcn_s_barrier();
  int cur = 0;

  f4 sum = f4{0.f, 0.f, 0.f, 0.f};
  for (int it = 0; it < 16; ++it) {
    if (it + 1 < 16) {
      const unsigned short* gn = g0 + (long)(it + 1) * 128 * D_;
      unsigned short* nb = lds + (cur ^ 1) * 8192;
      stage16(gn, nb + tid * 8);
      stage16(gn + 32, nb + 4096 + tid * 8);
    }
    const unsigned short* base = lds + cur * 8192;
    __builtin_amdgcn_s_setprio(1);
#pragma unroll
    for (int tt = 0; tt < 8; ++tt) {
      bf8 b0 = ldb(base + tt * 512 + lane * 8);
      bf8 b1 = ldb(base + 4096 + tt * 512 + lane * 8);
      f4 d = f4{0.f, 0.f, 0.f, 0.f};
      d = MFMA(a0, b0, d);
      d = MFMA(a1, b1, d);
#pragma unroll
      for (int r = 0; r < 4; ++r) sum[r] += __builtin_amdgcn_exp2f(d[r]);
    }
    __builtin_amdgcn_s_setprio(0);
    if (it + 1 < 16) {
      asm volatile("s_waitcnt vmcnt(0)" ::: "memory");
      __builtin_amdgcn_s_barrier();
      cur ^= 1;
    }
  }
#pragma unroll
  for (int m = 1; m < 16; m <<= 1) {
#pragma unroll
    for (int r = 0; r < 4; ++r) sum[r] += __shfl_xor(sum[r], m, 64);
  }
  if (l15 == 0) {
    float* rp = recip + (long)(b * H_ + h) * S_ + s0 + quad * 4;
#pragma unroll
    for (int r = 0; r < 4; ++r) rp[r] = 1.0f / (16.0f * sum[r]);
  }
}

// ---- pass 2: attn_mean[b,s,t] = sum_h recip[b,h,s]*exp2(score) ----
// 1D grid 512, block 512 (8 waves); XCD-swizzled decode (r8). r9: Q-frag register
// pipelining -- load h+1's a0n/a1n/rpn BEFORE issuing h+1's stage16 (sched_barrier pins
// the order), compute consumes preloaded a0/a1/rp with no VMEM wait, rotate after the
// barrier. In-order vmcnt then never gates compute on staging return.
__global__ __launch_bounds__(512) void k_attn(
    const unsigned short* __restrict__ qsb, const unsigned short* __restrict__ ksb,
    const float* __restrict__ recip, float* __restrict__ am) {
  __shared__ unsigned short lds[16384];         // 2 x (128 t-rows x 64 dk) per head
  const int tid = threadIdx.x, wave = tid >> 6, lane = tid & 63;
  const int l15 = lane & 15, quad = lane >> 4;
  const int n = blockIdx.x, xcd = n & 7, slot = n >> 3;
  const int b = xcd >> 2;
  const int tchunk = ((xcd & 1) << 3) | (slot & 7);
  const int stile = (((xcd >> 1) & 1) << 3) | (slot >> 3);
  const int s0 = stile * 128 + wave * 16;
  const int t0c = tchunk * 128;

  f4 acc[8];
#pragma unroll
  for (int tt = 0; tt < 8; ++tt) acc[tt] = f4{0.f, 0.f, 0.f, 0.f};

  const unsigned short* qbase = qsb + ((long)(b * S_) + s0 + l15) * D_ + quad * 8;
  // staging decode for u = tid (sh2=0) and u = tid+512 (sh2=1): stt=(tid>>6)&7
  const int sl15 = tid & 15, squad = (tid >> 4) & 3, stt = (tid >> 6) & 7;
  const unsigned short* g0 =
      ksb + ((long)(b * S_) + t0c + stt * 16 + sl15) * D_ + squad * 8;
  const float* rbase = recip + (long)(b * H_) * S_ + s0 + quad * 4;

  // prologue: stage head 0 into buf0; load head 0's Q-frags + recip
  stage16(g0, lds + tid * 8);
  stage16(g0 + 32, lds + 4096 + tid * 8);
  bf8 a0 = ldb(qbase);
  bf8 a1 = ldb(qbase + 32);
  f4 rp = *reinterpret_cast<const f4*>(rbase);
  asm volatile("s_waitcnt vmcnt(0)" ::: "memory");
  __builtin_amdgcn_s_barrier();
  int cur = 0;

  for (int h = 0; h < H_; ++h) {
    bf8 a0n, a1n;
    f4 rpn;
    if (h + 1 < H_) {
      // register prefetch for head h+1 -- ISSUED BEFORE the stage16s so the in-order
      // vmcnt wait for these regs (next iteration) never includes staging returns.
      a0n = ldb(qbase + (h + 1) * 64);
      a1n = ldb(qbase + (h + 1) * 64 + 32);
      rpn = *reinterpret_cast<const f4*>(rbase + (long)(h + 1) * S_);
      __builtin_amdgcn_sched_barrier(0);        // pin: reg loads above, staging below
      const unsigned short* gn = g0 + (h + 1) * 64;
      unsigned short* nb = lds + (cur ^ 1) * 8192;
      stage16(gn, nb + tid * 8);
      stage16(gn + 32, nb + 4096 + tid * 8);
    }
    const unsigned short* base = lds + cur * 8192;
    __builtin_amdgcn_s_setprio(1);
#pragma unroll
    for (int tt = 0; tt < 8; ++tt) {
      bf8 b0 = ldb(base + tt * 512 + lane * 8);
      bf8 b1 = ldb(base + 4096 + tt * 512 + lane * 8);
      f4 d = f4{0.f, 0.f, 0.f, 0.f};
      d = MFMA(a0, b0, d);
      d = MFMA(a1, b1, d);
#pragma unroll
      for (int r = 0; r < 4; ++r) acc[tt][r] += rp[r] * __builtin_amdgcn_exp2f(d[r]);
    }
    __builtin_amdgcn_s_setprio(0);
    if (h + 1 < H_) {
      asm volatile("s_waitcnt vmcnt(0)" ::: "memory");
      __builtin_amdgcn_s_barrier();
      cur ^= 1;
      a0 = a0n;
      a1 = a1n;
      rp = rpn;
    }
  }
  float* obase = am + ((long)b * S_ + s0 + quad * 4) * S_ + t0c + l15;
#pragma unroll
  for (int tt = 0; tt < 8; ++tt)
#pragma unroll
    for (int r = 0; r < 4; ++r) obase[(long)r * S_ + tt * 16] = acc[tt][r];
}

// ---- head split-K: ph[kc][row][64] f32 = am-chunk @ vs-chunk, kc chunk = 512 t ----
// grid (64 rowgroups, 4 kc), block 256
__global__ __launch_bounds__(256) void k_hpart(
    const float* __restrict__ am, const unsigned short* __restrict__ vst,
    float* __restrict__ ph) {
  const int tid = threadIdx.x, wave = tid >> 6, lane = tid & 63;
  const int l15 = lane & 15, quad = lane >> 4;
  const int rg = blockIdx.x, kc = blockIdx.y;
  const int row0 = rg * 64 + wave * 16;
  const int b = row0 >> 11;
  const float* arow = am + (long)(row0 + l15) * S_ + kc * 512 + quad * 8;
  const unsigned short* vb = vst + (long)b * DK_ * S_ + kc * 512 + quad * 8;
  f4 acc[4];
  for (int i = 0; i < 4; ++i) acc[i] = f4{0.f, 0.f, 0.f, 0.f};
  for (int t0 = 0; t0 < 512; t0 += 32) {
    f4 alo = *reinterpret_cast<const f4*>(arow + t0);
    f4 ahi = *reinterpret_cast<const f4*>(arow + t0 + 4);
    bf8 a = pack_bf8(alo, ahi);
#pragma unroll
    for (int i = 0; i < 4; ++i) {
      bf8 bf = ldb(vb + (long)(i * 16 + l15) * S_ + t0);
      acc[i] = MFMA(a, bf, acc[i]);
    }
  }
#pragma unroll
  for (int i = 0; i < 4; ++i)
#pragma unroll
    for (int r = 0; r < 4; ++r)
      ph[((long)kc * 4096 + row0 + quad * 4 + r) * 64 + i * 16 + l15] = acc[i][r];
}

// reduce -> headb bf16 [row][64] (fully coalesced)
__global__ void k_hred(const float* __restrict__ ph, unsigned short* __restrict__ headb) {
  int e = blockIdx.x * 256 + threadIdx.x;      // e = row*64 + dk
  float s = ph[e] + ph[e + 4096 * 64] + ph[e + 2 * 4096 * 64] + ph[e + 3 * 4096 * 64];
  headb[e] = f2bf_bits(s);
}

// ---- out = head @ Wo ----
// grid (8 d-chunks of 128, 32 s-tiles of 64, B), block 256
__global__ __launch_bounds__(256) void k_out(
    const unsigned short* __restrict__ head, const unsigned short* __restrict__ wot,
    float* __restrict__ out) {
  const int tid = threadIdx.x, wave = tid >> 6, lane = tid & 63;
  const int l15 = lane & 15, quad = lane >> 4;
  const int dchunk = blockIdx.x, stile = blockIdx.y, b = blockIdx.z;
  const int s0 = stile * 64 + wave * 16;
  const int n0 = dchunk * 128;
  const unsigned short* hrow = head + ((long)b * S_ + s0 + l15) * DK_ + quad * 8;
  bf8 a0 = ldb(hrow);
  bf8 a1 = ldb(hrow + 32);
  const unsigned short* wb = wot + quad * 8;
  float* obase = out + ((long)b * S_ + s0 + quad * 4) * D_ + n0 + l15;
#pragma unroll
  for (int i = 0; i < 8; ++i) {
    const unsigned short* wp = wb + (long)(n0 + i * 16 + l15) * DK_;
    bf8 b0 = ldb(wp);
    bf8 b1 = ldb(wp + 32);
    f4 d = f4{0.f, 0.f, 0.f, 0.f};
    d = MFMA(a0, b0, d);
    d = MFMA(a1, b1, d);
#pragma unroll
    for (int r = 0; r < 4; ++r) obase[(long)r * D_ + i * 16] = d[r];
  }
}

extern "C" void kernel_launch(void* const* d_in, const int* in_sizes, int n_in,
                              void* d_out, int out_size, void* d_ws, size_t ws_size,
                              hipStream_t stream) {
  const float* q  = (const float*)d_in[0];
  const float* k  = (const float*)d_in[1];
  const float* v  = (const float*)d_in[2];
  const float* Wq = (const float*)d_in[3];
  const float* Wk = (const float*)d_in[4];
  const float* Wv = (const float*)d_in[5];
  const float* Wo = (const float*)d_in[6];

  float* out = (float*)d_out;                       // [B,S,D] = 4,194,304 f32
  float* am  = out + (long)B_ * S_ * D_;            // [B,S,S] = 8,388,608 f32

  // workspace (~22.5 MB)
  unsigned short* qsb  = (unsigned short*)d_ws;     // [4096][1024]
  unsigned short* ksb  = qsb + 4194304;
  unsigned short* wqt  = ksb + 4194304;             // [1024][1024]
  unsigned short* wkt  = wqt + 1048576;
  unsigned short* wvt  = wkt + 1048576;             // [64][1024]
  unsigned short* wot  = wvt + 65536;               // [1024][64]
  unsigned short* vst  = wot + 65536;               // [B][64][S]
  unsigned short* headb= vst + 262144;              // [4096][64]
  float* recip = (float*)(headb + 262144);          // [B*H*S]

  // bf16 q,k copies live in the am region of d_out (dead before k_attn writes am)
  unsigned short* qb = (unsigned short*)am;         // [4096][1024]
  unsigned short* kb = qb + 4194304;
  // split-K f32 partials [4][4096][64] live in the out region (dead until k_out)
  float* part = out;

  k_prep<<<4384, 256, 0, stream>>>(q, k, Wq, Wk, Wv, Wo, qb, kb, wqt, wkt, wvt, wot);
  k_gemm_qk<<<dim3(32, 8, 2), 256, 0, stream>>>(qb, kb, wqt, wkt, qsb, ksb);
  k_pv<<<dim3(64, 4), 256, 0, stream>>>(v, wvt, part);
  k_vred<<<1024, 256, 0, stream>>>(part, vst);
  k_denom<<<512, 512, 0, stream>>>(qsb, ksb, recip);
  k_attn<<<512, 512, 0, stream>>>(qsb, ksb, recip, am);
  k_hpart<<<dim3(64, 4), 256, 0, stream>>>(am, vst, part);
  k_hred<<<1024, 256, 0, stream>>>(part, headb);
  k_out<<<dim3(8, 32, 2), 256, 0, stream>>>(headb, wot, out);
}